// Round 16
// baseline (141.164 us; speedup 1.0000x reference)
//
#include <hip/hip_runtime.h>
#include <hip/hip_bf16.h>
#include <cstdint>

// ---------------------------------------------------------------------------
// GAT forward, N=4096, F=512, D=64, H=8, O=128, fp32 in/out.
// Identity: exp(lrelu(u)) = max(exp(u), exp(0.2u)); u = s1_i+s2_j rank-1;
// softmax row-scale invariance => p'_ij = max(E2_j, g_i*F2_j), g=exp(-0.8 s1).
// Round-16 = Round-15 with the cvt_pkrtz return-type fix (builtin returns
// __fp16 ext_vector(2); capture with auto, bit_cast the 4B value to u32).
//   (1) P-pack via __builtin_amdgcn_cvt_pkrtz after f32 mul/max/cndmask.
//   (2) all agg constants templated -> strength-reduced addressing.
// ---------------------------------------------------------------------------

using bf16_t = __bf16;
using half_t = _Float16;
using bf16x4 = __attribute__((ext_vector_type(4))) __bf16;
using bf16x8 = __attribute__((ext_vector_type(8))) __bf16;
using f16x4  = __attribute__((ext_vector_type(4))) _Float16;
using f16x8  = __attribute__((ext_vector_type(8))) _Float16;
using f32x4  = __attribute__((ext_vector_type(4))) float;
using u32x4  = __attribute__((ext_vector_type(4))) uint32_t;

#define LOG2E 1.44269504f
constexpr int NN = 4096;

// ---- pack adjacency into TRANSPOSED bitmask: bitsT[(j>>5)*N + i], bit j&31
__global__ __launch_bounds__(256) void pack_bits_k(const int* __restrict__ adj,
                                                   uint32_t* __restrict__ bitsT, int total) {
    int stride = gridDim.x * blockDim.x;
    for (int idx = blockIdx.x * blockDim.x + threadIdx.x; idx < total; idx += stride) {
        unsigned long long m = __ballot(adj[idx] > 0);
        int l = threadIdx.x & 63;
        int i = idx >> 12, j = idx & 4095;
        if (l == 0)        bitsT[(size_t)(j >> 5) * NN + i] = (uint32_t)m;
        else if (l == 32)  bitsT[(size_t)(j >> 5) * NN + i] = (uint32_t)(m >> 32);
    }
}

// ---- prep: x -> xbt (K-tiled bf16 [kc][4096][32]),
//            W_heads -> WT1t ([kc][512][32]), W_out -> WoutT[o][512] row-major
__global__ __launch_bounds__(256) void prep_k(const float* __restrict__ x,
                                              const float* __restrict__ Wh,
                                              const float* __restrict__ Wo,
                                              bf16_t* __restrict__ xbt,
                                              bf16_t* __restrict__ WT1t,
                                              bf16_t* __restrict__ WoutT) {
    const int NXT = NN * 512 / 8;
    const int NWT = 512 * 512 / 8;
    const int NW2 = 128 * 512;
    int stride = gridDim.x * blockDim.x;
    for (int t = blockIdx.x * blockDim.x + threadIdx.x; t < NXT + NWT + NW2; t += stride) {
        if (t < NXT) {
            size_t d = (size_t)t * 8;
            int kc = (int)(d >> 17);
            int rem = (int)(d & 131071);
            int i = rem >> 5, k0 = rem & 31;
            const float* sp = x + (size_t)i * 512 + kc * 32 + k0;
            f32x4 s0 = *(const f32x4*)sp;
            f32x4 s1 = *(const f32x4*)(sp + 4);
            bf16x8 o;
#pragma unroll
            for (int e = 0; e < 4; ++e) { o[e] = (bf16_t)s0[e]; o[4 + e] = (bf16_t)s1[e]; }
            *(bf16x8*)(xbt + d) = o;
        } else if (t < NXT + NWT) {
            size_t d = (size_t)(t - NXT) * 8;
            int kc = (int)(d >> 14);
            int rem = (int)(d & 16383);
            int col = rem >> 5, k0 = rem & 31;
            int h = col >> 6, dd = col & 63;
            bf16x8 o;
#pragma unroll
            for (int e = 0; e < 8; ++e)
                o[e] = (bf16_t)Wh[(size_t)(h << 15) + (size_t)(kc * 32 + k0 + e) * 64 + dd];
            *(bf16x8*)(WT1t + d) = o;
        } else {
            int u = t - NXT - NWT;
            int o2 = u >> 9, cc = u & 511;
            WoutT[u] = (bf16_t)Wo[cc * 128 + o2];
        }
    }
}

// ---- bf16 MFMA GEMM, 4 waves/block, wave = 16 rows x 64 cols.
// TILED=1: A/B read K-tiled [kc][row|col][32]; TILED=0: row-major (gemm2).
// CS: epilogue writes VTt as F16 (j-tiled [i>>5][col][i&31]) + g/E2/F2.
// WC: writes fp32 partial C slice (split-K via blockIdx.z)
template<int CS, int WC, int TILED>
__global__ __launch_bounds__(256) void gemm_k(const bf16_t* __restrict__ A,
                                              const bf16_t* __restrict__ BT,
                                              half_t* __restrict__ VTt,
                                              float* __restrict__ Cp,
                                              const float* __restrict__ a1,
                                              const float* __restrict__ a2,
                                              float* __restrict__ g1,
                                              float* __restrict__ E2,
                                              float* __restrict__ F2,
                                              int K, int NC, int kslice, int NCOLS) {
    const int wave = threadIdx.x >> 6, lane = threadIdx.x & 63;
    const int lr = lane & 15, kg = lane >> 4;
    const int rowb = (blockIdx.x * 4 + wave) * 16, cb = blockIdx.y * 64, kz = blockIdx.z;
    f32x4 acc[4];
#pragma unroll
    for (int dt = 0; dt < 4; ++dt) acc[dt] = 0.0f;
    const int k0beg = kz * kslice, k0end = k0beg + kslice;
    for (int k0 = k0beg; k0 < k0end; k0 += 32) {
        bf16x8 af;
        if (TILED) {
            const int kc = k0 >> 5;
            af = *(const bf16x8*)(A + (size_t)kc * (NN * 32) + (size_t)(rowb + lr) * 32 + kg * 8);
        } else {
            af = *(const bf16x8*)(A + (size_t)(rowb + lr) * K + k0 + kg * 8);
        }
#pragma unroll
        for (int dt = 0; dt < 4; ++dt) {
            bf16x8 bfr;
            if (TILED) {
                const int kc = k0 >> 5;
                bfr = *(const bf16x8*)(BT + (size_t)kc * (NC * 32) +
                                       (size_t)(cb + dt * 16 + lr) * 32 + kg * 8);
            } else {
                bfr = *(const bf16x8*)(BT + (size_t)(cb + dt * 16 + lr) * K + k0 + kg * 8);
            }
            acc[dt] = __builtin_amdgcn_mfma_f32_16x16x32_bf16(af, bfr, acc[dt], 0, 0, 0);
        }
    }
    if (WC) {
#pragma unroll
        for (int dt = 0; dt < 4; ++dt)
#pragma unroll
            for (int r = 0; r < 4; ++r)
                Cp[((size_t)kz * NN + rowb + kg * 4 + r) * NC + cb + dt * 16 + lr] = acc[dt][r];
    }
    if (CS) {
        const int i0 = rowb + kg * 4;
        const size_t tbase = (size_t)(i0 >> 5) * NCOLS * 32 + (i0 & 31);
#pragma unroll
        for (int dt = 0; dt < 4; ++dt) {
            f16x4 v;
#pragma unroll
            for (int r = 0; r < 4; ++r) v[r] = (half_t)acc[dt][r];
            *(f16x4*)(VTt + tbase + (size_t)(cb + dt * 16 + lr) * 32) = v;
        }
        float a1v[4], a2v[4];
#pragma unroll
        for (int dt = 0; dt < 4; ++dt) {
            a1v[dt] = a1[cb + dt * 16 + lr];
            a2v[dt] = a2[cb + dt * 16 + lr];
        }
#pragma unroll
        for (int r = 0; r < 4; ++r) {
            float d1 = 0.f, d2 = 0.f;
#pragma unroll
            for (int dt = 0; dt < 4; ++dt) { d1 += acc[dt][r] * a1v[dt]; d2 += acc[dt][r] * a2v[dt]; }
#pragma unroll
            for (int o = 1; o < 16; o <<= 1) { d1 += __shfl_xor(d1, o); d2 += __shfl_xor(d2, o); }
            if (lr == 0) {
                size_t row = (size_t)blockIdx.y * NN + rowb + kg * 4 + r;
                g1[row] = exp2f(-0.8f * LOG2E * d1);
                E2[row] = exp2f(LOG2E * d2);
                F2[row] = exp2f(0.2f * LOG2E * d2);
            }
        }
    }
}

// ---- fused attention-aggregate (R14 structure, fully templated + pkrtz).
// grid = (CG*JZG, 64); x -> (c = x/JZG, jzgrp = x%JZG); y = rowtile.
// 4 waves/block; wave w owns jz = jzgrp*4 + w; wave = 64 rows x 64 cols.
// p'_ij = adj ? max(E2_j, g_i*F2_j) : 0  (f32 math, cndmask, cvt_pkrtz pack).
// Z row-sums via extra f16 MFMA against a ones-column B-fragment.
template<int JZG, int JR, int CT, int ZC, int SH, int TS>
__global__ __launch_bounds__(256) void gat_agg_k(const float* __restrict__ g1,
                                                 const float* __restrict__ E2,
                                                 const float* __restrict__ F2,
                                                 const uint32_t* __restrict__ bitsT,
                                                 const half_t* __restrict__ VTt,
                                                 bf16_t* __restrict__ Hpart,
                                                 float* __restrict__ zpart) {
    constexpr int STEPS = JR / 32;
    const int wave = threadIdx.x >> 6, lane = threadIdx.x & 63;
    const int lr = lane & 15, kg = lane >> 4;
    const int c = blockIdx.x / JZG, jzg = blockIdx.x % JZG;
    const int rowb = blockIdx.y * 64;
    const int jz = jzg * 4 + wave;
    const int cb = c * 64;
    const float* gp  = g1 + (size_t)SH * c;
    const float* E2p = E2 + (size_t)SH * c;
    const float* F2p = F2 + (size_t)SH * c;
    const int jb0 = jz * JR;

    f32x4 acc[4][4], accz[4];
#pragma unroll
    for (int rt = 0; rt < 4; ++rt) {
        accz[rt] = 0.0f;
#pragma unroll
        for (int dt = 0; dt < 4; ++dt) acc[rt][dt] = 0.0f;
    }
    float gv[4];
#pragma unroll
    for (int rt = 0; rt < 4; ++rt) gv[rt] = gp[rowb + rt * 16 + lr];
    f16x8 ones;
#pragma unroll
    for (int e = 0; e < 8; ++e) ones[e] = (half_t)(lr == 0 ? 1.0f : 0.0f);

    auto LOAD = [&](int jb, f16x8* bfr, f32x4& e2a, f32x4& e2b, f32x4& f2a, f32x4& f2b,
                    uint32_t* bw) {
        const int jk = jb + kg * 8;
        const int jc = jb >> 5;
        e2a = *(const f32x4*)(E2p + jk);
        e2b = *(const f32x4*)(E2p + jk + 4);
        f2a = *(const f32x4*)(F2p + jk);
        f2b = *(const f32x4*)(F2p + jk + 4);
        const half_t* vb = VTt + (size_t)jc * TS + kg * 8;
#pragma unroll
        for (int dt = 0; dt < 4; ++dt)
            bfr[dt] = *(const f16x8*)(vb + (size_t)(cb + dt * 16 + lr) * 32);
        const uint32_t* bb = bitsT + (size_t)jc * NN + rowb;
#pragma unroll
        for (int rt = 0; rt < 4; ++rt)
            bw[rt] = bb[rt * 16 + lr];
    };
    auto COMP = [&](const f16x8* bfr, f32x4 e2a, f32x4 e2b, f32x4 f2a, f32x4 f2b,
                    const uint32_t* bw) {
#pragma unroll
        for (int rt = 0; rt < 4; ++rt) {
            uint32_t mb = (bw[rt] >> (kg * 8)) & 0xffu;
            float pv[8];
#pragma unroll
            for (int e = 0; e < 8; ++e) {
                float e2 = (e < 4) ? e2a[e] : e2b[e - 4];
                float f2 = (e < 4) ? f2a[e] : f2b[e - 4];
                float p = fmaxf(e2, gv[rt] * f2);
                pv[e] = (mb & (1u << e)) ? p : 0.0f;
            }
            u32x4 af_u;
#pragma unroll
            for (int p = 0; p < 4; ++p) {
                auto pk = __builtin_amdgcn_cvt_pkrtz(pv[2 * p], pv[2 * p + 1]);
                af_u[p] = __builtin_bit_cast(uint32_t, pk);
            }
            f16x8 af = __builtin_bit_cast(f16x8, af_u);
#pragma unroll
            for (int dt = 0; dt < 4; ++dt)
                acc[rt][dt] = __builtin_amdgcn_mfma_f32_16x16x32_f16(af, bfr[dt], acc[rt][dt], 0, 0, 0);
            accz[rt] = __builtin_amdgcn_mfma_f32_16x16x32_f16(af, ones, accz[rt], 0, 0, 0);
        }
    };

    f16x8 bA[4], bB[4];
    f32x4 eaA, ebA, faA, fbA, eaB, ebB, faB, fbB;
    uint32_t wA[4], wB[4];
    LOAD(jb0, bA, eaA, ebA, faA, fbA, wA);
#pragma unroll 1
    for (int js = 0; js < STEPS - 2; js += 2) {
        LOAD(jb0 + (js + 1) * 32, bB, eaB, ebB, faB, fbB, wB);
        COMP(bA, eaA, ebA, faA, fbA, wA);
        LOAD(jb0 + (js + 2) * 32, bA, eaA, ebA, faA, fbA, wA);
        COMP(bB, eaB, ebB, faB, fbB, wB);
    }
    LOAD(jb0 + (STEPS - 1) * 32, bB, eaB, ebB, faB, fbB, wB);
    COMP(bA, eaA, ebA, faA, fbA, wA);
    COMP(bB, eaB, ebB, faB, fbB, wB);

    bf16_t* Hp = Hpart + (size_t)jz * NN * CT;
#pragma unroll
    for (int rt = 0; rt < 4; ++rt) {
#pragma unroll
        for (int dt = 0; dt < 4; ++dt)
#pragma unroll
            for (int r = 0; r < 4; ++r)
                Hp[(size_t)(rowb + rt * 16 + kg * 4 + r) * CT + cb + dt * 16 + lr] = (bf16_t)acc[rt][dt][r];
    }
    if (lr == 0 && (ZC > 1 || c == 0)) {
        int zi = jz * ZC + (ZC > 1 ? c : 0);
#pragma unroll
        for (int rt = 0; rt < 4; ++rt)
#pragma unroll
            for (int r = 0; r < 4; ++r)
                zpart[(size_t)zi * NN + rowb + rt * 16 + kg * 4 + r] = accz[rt][r];
    }
}

// ---- finalize layer 1: hcatb = bf16(ELU(sum H / sum Z)), 8 cols/thread
__global__ __launch_bounds__(256) void fin1_k(const bf16_t* __restrict__ Hpart,
                                              const float* __restrict__ zpart,
                                              bf16_t* __restrict__ hcatb) {
    int idx = blockIdx.x * 256 + threadIdx.x;   // < N*64
    int i = idx >> 6, col0 = (idx & 63) << 3, h = col0 >> 6;
    float Z = 0.f;
#pragma unroll
    for (int jz = 0; jz < 4; ++jz) Z += zpart[(size_t)(jz * 8 + h) * NN + i];
    float hs[8];
#pragma unroll
    for (int e = 0; e < 8; ++e) hs[e] = 0.f;
#pragma unroll
    for (int jz = 0; jz < 4; ++jz) {
        bf16x8 v = *(const bf16x8*)(Hpart + ((size_t)jz * NN + i) * 512 + col0);
#pragma unroll
        for (int e = 0; e < 8; ++e) hs[e] += (float)v[e];
    }
    float invZ = 1.0f / Z;
    bf16x8 o;
#pragma unroll
    for (int e = 0; e < 8; ++e) {
        float v = hs[e] * invZ;
        o[e] = (bf16_t)(v > 0.f ? v : expm1f(v));
    }
    *(bf16x8*)(hcatb + (size_t)i * 512 + col0) = o;
}

// ---- combine split-K gemm2 slices: VT2t (j-tiled f16) + g/E2/F2. 128thr=1 row.
__global__ __launch_bounds__(128) void comb2_k(const float* __restrict__ Cp,
                                               const float* __restrict__ a1o,
                                               const float* __restrict__ a2o,
                                               half_t* __restrict__ VT2t,
                                               float* __restrict__ g1o,
                                               float* __restrict__ E2o,
                                               float* __restrict__ F2o) {
    int r = blockIdx.x, t = threadIdx.x;
    float w = 0.f;
#pragma unroll
    for (int z = 0; z < 4; ++z) w += Cp[((size_t)z * NN + r) * 128 + t];
    VT2t[(size_t)(r >> 5) * (128 * 32) + t * 32 + (r & 31)] = (half_t)w;
    float d1 = w * a1o[t], d2 = w * a2o[t];
#pragma unroll
    for (int o = 1; o < 64; o <<= 1) { d1 += __shfl_xor(d1, o); d2 += __shfl_xor(d2, o); }
    __shared__ float red[4];
    if ((t & 63) == 0) { red[(t >> 6) * 2 + 0] = d1; red[(t >> 6) * 2 + 1] = d2; }
    __syncthreads();
    if (t == 0) {
        float s1 = red[0] + red[2], s2 = red[1] + red[3];
        g1o[r] = exp2f(-0.8f * LOG2E * s1);
        E2o[r] = exp2f(LOG2E * s2);
        F2o[r] = exp2f(0.2f * LOG2E * s2);
    }
}

// ---- finalize layer 2: out fp32 = sum H / sum Z, 8 cols/thread
__global__ __launch_bounds__(256) void fin2_k(const bf16_t* __restrict__ Hpart,
                                              const float* __restrict__ zpart,
                                              float* __restrict__ out) {
    int idx = blockIdx.x * 256 + threadIdx.x;   // < N*16
    int i = idx >> 4, col0 = (idx & 15) << 3;
    float Z = 0.f;
#pragma unroll
    for (int jz = 0; jz < 16; ++jz) Z += zpart[(size_t)jz * NN + i];
    float hs[8];
#pragma unroll
    for (int e = 0; e < 8; ++e) hs[e] = 0.f;
#pragma unroll
    for (int jz = 0; jz < 16; ++jz) {
        bf16x8 v = *(const bf16x8*)(Hpart + ((size_t)jz * NN + i) * 128 + col0);
#pragma unroll
        for (int e = 0; e < 8; ++e) hs[e] += (float)v[e];
    }
    float invZ = 1.0f / Z;
    f32x4 o0, o1;
#pragma unroll
    for (int e = 0; e < 4; ++e) { o0[e] = hs[e] * invZ; o1[e] = hs[e + 4] * invZ; }
    *(f32x4*)(out + (size_t)i * 128 + col0) = o0;
    *(f32x4*)(out + (size_t)i * 128 + col0 + 4) = o1;
}

extern "C" void kernel_launch(void* const* d_in, const int* in_sizes, int n_in,
                              void* d_out, int out_size, void* d_ws, size_t ws_size,
                              hipStream_t stream) {
    const int N = 4096;
    const float* x       = (const float*)d_in[0];
    const int*   adj     = (const int*)d_in[1];
    const float* W_heads = (const float*)d_in[2];
    const float* a1h     = (const float*)d_in[3];
    const float* a2h     = (const float*)d_in[4];
    const float* W_out   = (const float*)d_in[5];
    const float* a1o     = (const float*)d_in[6];
    const float* a2o     = (const float*)d_in[7];
    (void)in_sizes; (void)n_in; (void)out_size; (void)ws_size;

    size_t off = 0;
    auto alloc = [&](size_t bytes) { size_t o = off; off = (off + bytes + 255) & ~(size_t)255; return o; };
    char* ws = (char*)d_ws;
    uint32_t* bitsT = (uint32_t*)(ws + alloc((size_t)N * N / 8));        // 2 MB
    half_t* VT1t    = (half_t*)(ws + alloc((size_t)512 * N * 2));        // 4 MB (j-tiled f16)
    bf16_t* hcatb   = (bf16_t*)(ws + alloc((size_t)N * 512 * 2));        // 4 MB
    bf16_t* WoutT   = (bf16_t*)(ws + alloc((size_t)128 * 512 * 2));      // 128 KB
    float*  g1h     = (float*)(ws + alloc((size_t)8 * N * 4));
    float*  E2h     = (float*)(ws + alloc((size_t)8 * N * 4));
    float*  F2h     = (float*)(ws + alloc((size_t)8 * N * 4));
    float*  g1o     = (float*)(ws + alloc((size_t)N * 4));
    float*  E2o     = (float*)(ws + alloc((size_t)N * 4));
    float*  F2o     = (float*)(ws + alloc((size_t)N * 4));
    half_t* VT2t    = (half_t*)(ws + alloc((size_t)128 * N * 2));        // 1 MB (j-tiled f16)
    float*  zpart   = (float*)(ws + alloc((size_t)64 * N * 4));          // 1 MB
    bf16_t* Hpart   = (bf16_t*)(ws + alloc((size_t)32 * 1024 * 1024));   // 32 MB (16 used L1)
    // aliases into the Hpart region (temporally disjoint):
    bf16_t* xbt   = (bf16_t*)Hpart;                       // 4 MB, dead after gemm1
    bf16_t* WT1t  = (bf16_t*)((char*)Hpart + (9 << 20));  // 0.5 MB, dead after gemm1
    float*  Cpart = (float*)Hpart;                        // gemm2..comb2 only

    // 1. adjacency bitmask (transposed)
    hipLaunchKernelGGL(pack_bits_k, dim3(2048), dim3(256), 0, stream, adj, bitsT, N * N);
    // 2. prep: K-tiled bf16 xbt/WT1t + row-major WoutT
    hipLaunchKernelGGL(prep_k, dim3(1024), dim3(256), 0, stream, x, W_heads, W_out, xbt, WT1t, WoutT);
    // 3. gemm1 (TILED inputs): VT1t (f16) + g/E2/F2 per head
    hipLaunchKernelGGL((gemm_k<1, 0, 1>), dim3(64, 8, 1), dim3(256), 0, stream,
                       xbt, WT1t, VT1t, (float*)nullptr, a1h, a2h, g1h, E2h, F2h, 512, 512, 512, 512);
    // 4. layer-1 aggregate: grid x=head(8), y=rowtile(64); jz = wave (0..3), JR=1024
    hipLaunchKernelGGL((gat_agg_k<1, 1024, 512, 8, 4096, 512 * 32>), dim3(8, 64, 1), dim3(256), 0, stream,
                       g1h, E2h, F2h, bitsT, VT1t, Hpart, zpart);
    // 5. finalize 1 -> hcatb
    hipLaunchKernelGGL(fin1_k, dim3(1024), dim3(256), 0, stream, Hpart, zpart, hcatb);
    // 6. gemm2 split-K=4 (row-major inputs) -> Cpart
    hipLaunchKernelGGL((gemm_k<0, 1, 0>), dim3(64, 2, 4), dim3(256), 0, stream,
                       hcatb, WoutT, (half_t*)nullptr, Cpart,
                       (const float*)nullptr, (const float*)nullptr,
                       (float*)nullptr, (float*)nullptr, (float*)nullptr, 512, 128, 128, 128);
    // 7. combine -> VT2t (f16), g1o/E2o/F2o
    hipLaunchKernelGGL(comb2_k, dim3(4096), dim3(128), 0, stream, Cpart, a1o, a2o, VT2t, g1o, E2o, F2o);
    // 8. layer-2 aggregate: grid x=(c,jzgrp)=8, y=rowtile(64); jz = jzgrp*4+wave
    hipLaunchKernelGGL((gat_agg_k<4, 256, 128, 1, 0, 128 * 32>), dim3(8, 64, 1), dim3(256), 0, stream,
                       g1o, E2o, F2o, bitsT, VT2t, Hpart, zpart);
    // 9. finalize 2 -> out
    hipLaunchKernelGGL(fin2_k, dim3(256), dim3(256), 0, stream, Hpart, zpart, (float*)d_out);
}

// Round 17
// 138.355 us; speedup vs baseline: 1.0203x; 1.0203x over previous
//
#include <hip/hip_runtime.h>
#include <hip/hip_bf16.h>
#include <cstdint>

// ---------------------------------------------------------------------------
// GAT forward, N=4096, F=512, D=64, H=8, O=128, fp32 in/out.
// Identity: exp(lrelu(u)) = max(exp(u), exp(0.2u)); u = s1_i+s2_j rank-1;
// softmax row-scale invariance => p'_ij = max(E2_j, g_i*F2_j), g=exp(-0.8 s1).
// Round-17 = Round-14 (proven 136.5us, agg1 47.0, VGPR 120) + occupancy fix:
//   layer-1 agg uses 8-WAVE blocks (waves = jz 0..7, JR=512) -> 16 waves/CU
//   (was 8) with the per-wave inner loop byte-identical to R14. Hpart back to
//   8 planes; fin1 8-plane reduction. No pkrtz, no packed-f16 math (R16/R11
//   lessons: reg-pressure + serial chains beat inst-count savings; ghost).
// ---------------------------------------------------------------------------

using bf16_t = __bf16;
using half_t = _Float16;
using bf16x4 = __attribute__((ext_vector_type(4))) __bf16;
using bf16x8 = __attribute__((ext_vector_type(8))) __bf16;
using f16x4  = __attribute__((ext_vector_type(4))) _Float16;
using f16x8  = __attribute__((ext_vector_type(8))) _Float16;
using f32x4  = __attribute__((ext_vector_type(4))) float;

#define LOG2E 1.44269504f
constexpr int NN = 4096;

// ---- pack adjacency into TRANSPOSED bitmask: bitsT[(j>>5)*N + i], bit j&31
__global__ __launch_bounds__(256) void pack_bits_k(const int* __restrict__ adj,
                                                   uint32_t* __restrict__ bitsT, int total) {
    int stride = gridDim.x * blockDim.x;
    for (int idx = blockIdx.x * blockDim.x + threadIdx.x; idx < total; idx += stride) {
        unsigned long long m = __ballot(adj[idx] > 0);
        int l = threadIdx.x & 63;
        int i = idx >> 12, j = idx & 4095;
        if (l == 0)        bitsT[(size_t)(j >> 5) * NN + i] = (uint32_t)m;
        else if (l == 32)  bitsT[(size_t)(j >> 5) * NN + i] = (uint32_t)(m >> 32);
    }
}

// ---- prep: x -> xbt (K-tiled bf16 [kc][4096][32]),
//            W_heads -> WT1t ([kc][512][32]), W_out -> WoutT[o][512] row-major
__global__ __launch_bounds__(256) void prep_k(const float* __restrict__ x,
                                              const float* __restrict__ Wh,
                                              const float* __restrict__ Wo,
                                              bf16_t* __restrict__ xbt,
                                              bf16_t* __restrict__ WT1t,
                                              bf16_t* __restrict__ WoutT) {
    const int NXT = NN * 512 / 8;
    const int NWT = 512 * 512 / 8;
    const int NW2 = 128 * 512;
    int stride = gridDim.x * blockDim.x;
    for (int t = blockIdx.x * blockDim.x + threadIdx.x; t < NXT + NWT + NW2; t += stride) {
        if (t < NXT) {
            size_t d = (size_t)t * 8;
            int kc = (int)(d >> 17);
            int rem = (int)(d & 131071);
            int i = rem >> 5, k0 = rem & 31;
            const float* sp = x + (size_t)i * 512 + kc * 32 + k0;
            f32x4 s0 = *(const f32x4*)sp;
            f32x4 s1 = *(const f32x4*)(sp + 4);
            bf16x8 o;
#pragma unroll
            for (int e = 0; e < 4; ++e) { o[e] = (bf16_t)s0[e]; o[4 + e] = (bf16_t)s1[e]; }
            *(bf16x8*)(xbt + d) = o;
        } else if (t < NXT + NWT) {
            size_t d = (size_t)(t - NXT) * 8;
            int kc = (int)(d >> 14);
            int rem = (int)(d & 16383);
            int col = rem >> 5, k0 = rem & 31;
            int h = col >> 6, dd = col & 63;
            bf16x8 o;
#pragma unroll
            for (int e = 0; e < 8; ++e)
                o[e] = (bf16_t)Wh[(size_t)(h << 15) + (size_t)(kc * 32 + k0 + e) * 64 + dd];
            *(bf16x8*)(WT1t + d) = o;
        } else {
            int u = t - NXT - NWT;
            int o2 = u >> 9, cc = u & 511;
            WoutT[u] = (bf16_t)Wo[cc * 128 + o2];
        }
    }
}

// ---- bf16 MFMA GEMM, 4 waves/block, wave = 16 rows x 64 cols.
// TILED=1: A/B read K-tiled [kc][row|col][32]; TILED=0: row-major (gemm2).
// CS: epilogue writes VTt as F16 (j-tiled [i>>5][col][i&31]) + g/E2/F2.
// WC: writes fp32 partial C slice (split-K via blockIdx.z)
template<int CS, int WC, int TILED>
__global__ __launch_bounds__(256) void gemm_k(const bf16_t* __restrict__ A,
                                              const bf16_t* __restrict__ BT,
                                              half_t* __restrict__ VTt,
                                              float* __restrict__ Cp,
                                              const float* __restrict__ a1,
                                              const float* __restrict__ a2,
                                              float* __restrict__ g1,
                                              float* __restrict__ E2,
                                              float* __restrict__ F2,
                                              int K, int NC, int kslice, int NCOLS) {
    const int wave = threadIdx.x >> 6, lane = threadIdx.x & 63;
    const int lr = lane & 15, kg = lane >> 4;
    const int rowb = (blockIdx.x * 4 + wave) * 16, cb = blockIdx.y * 64, kz = blockIdx.z;
    f32x4 acc[4];
#pragma unroll
    for (int dt = 0; dt < 4; ++dt) acc[dt] = 0.0f;
    const int k0beg = kz * kslice, k0end = k0beg + kslice;
    for (int k0 = k0beg; k0 < k0end; k0 += 32) {
        bf16x8 af;
        if (TILED) {
            const int kc = k0 >> 5;
            af = *(const bf16x8*)(A + (size_t)kc * (NN * 32) + (size_t)(rowb + lr) * 32 + kg * 8);
        } else {
            af = *(const bf16x8*)(A + (size_t)(rowb + lr) * K + k0 + kg * 8);
        }
#pragma unroll
        for (int dt = 0; dt < 4; ++dt) {
            bf16x8 bfr;
            if (TILED) {
                const int kc = k0 >> 5;
                bfr = *(const bf16x8*)(BT + (size_t)kc * (NC * 32) +
                                       (size_t)(cb + dt * 16 + lr) * 32 + kg * 8);
            } else {
                bfr = *(const bf16x8*)(BT + (size_t)(cb + dt * 16 + lr) * K + k0 + kg * 8);
            }
            acc[dt] = __builtin_amdgcn_mfma_f32_16x16x32_bf16(af, bfr, acc[dt], 0, 0, 0);
        }
    }
    if (WC) {
#pragma unroll
        for (int dt = 0; dt < 4; ++dt)
#pragma unroll
            for (int r = 0; r < 4; ++r)
                Cp[((size_t)kz * NN + rowb + kg * 4 + r) * NC + cb + dt * 16 + lr] = acc[dt][r];
    }
    if (CS) {
        const int i0 = rowb + kg * 4;
        const size_t tbase = (size_t)(i0 >> 5) * NCOLS * 32 + (i0 & 31);
#pragma unroll
        for (int dt = 0; dt < 4; ++dt) {
            f16x4 v;
#pragma unroll
            for (int r = 0; r < 4; ++r) v[r] = (half_t)acc[dt][r];
            *(f16x4*)(VTt + tbase + (size_t)(cb + dt * 16 + lr) * 32) = v;
        }
        float a1v[4], a2v[4];
#pragma unroll
        for (int dt = 0; dt < 4; ++dt) {
            a1v[dt] = a1[cb + dt * 16 + lr];
            a2v[dt] = a2[cb + dt * 16 + lr];
        }
#pragma unroll
        for (int r = 0; r < 4; ++r) {
            float d1 = 0.f, d2 = 0.f;
#pragma unroll
            for (int dt = 0; dt < 4; ++dt) { d1 += acc[dt][r] * a1v[dt]; d2 += acc[dt][r] * a2v[dt]; }
#pragma unroll
            for (int o = 1; o < 16; o <<= 1) { d1 += __shfl_xor(d1, o); d2 += __shfl_xor(d2, o); }
            if (lr == 0) {
                size_t row = (size_t)blockIdx.y * NN + rowb + kg * 4 + r;
                g1[row] = exp2f(-0.8f * LOG2E * d1);
                E2[row] = exp2f(LOG2E * d2);
                F2[row] = exp2f(0.2f * LOG2E * d2);
            }
        }
    }
}

// ---- fused attention-aggregate (R14 inner loop, NW waves/block).
// grid = (CG*JZG, 64); x -> (c = x/JZG, jzg = x%JZG); y = rowtile.
// NW waves/block; wave w owns jz = jzg*NW + w; wave = 64 rows x 64 cols.
// p'_ij = adj ? max(E2_j, g_i*F2_j) : 0  (f32 math, cvt f16, cndmask mask).
// Z row-sums via extra f16 MFMA against a ones-column B-fragment.
template<int NW, int JZG>
__global__ __launch_bounds__(64 * NW) void gat_agg_k(const float* __restrict__ g1,
                                                     const float* __restrict__ E2,
                                                     const float* __restrict__ F2, int shead,
                                                     const uint32_t* __restrict__ bitsT,
                                                     const half_t* __restrict__ VTt,
                                                     bf16_t* __restrict__ Hpart,
                                                     float* __restrict__ zpart,
                                                     int CT, int JR, int ZC, int TS) {
    const int wave = threadIdx.x >> 6, lane = threadIdx.x & 63;
    const int lr = lane & 15, kg = lane >> 4;
    const int c = blockIdx.x / JZG, jzg = blockIdx.x % JZG;
    const int rowb = blockIdx.y * 64;
    const int jz = jzg * NW + wave;
    const int cb = c * 64;
    const float* gp  = g1 + (size_t)shead * c;
    const float* E2p = E2 + (size_t)shead * c;
    const float* F2p = F2 + (size_t)shead * c;
    const int steps = JR >> 5, jb0 = jz * JR;

    f32x4 acc[4][4], accz[4];
#pragma unroll
    for (int rt = 0; rt < 4; ++rt) {
        accz[rt] = 0.0f;
#pragma unroll
        for (int dt = 0; dt < 4; ++dt) acc[rt][dt] = 0.0f;
    }
    float gv[4];
#pragma unroll
    for (int rt = 0; rt < 4; ++rt) gv[rt] = gp[rowb + rt * 16 + lr];
    f16x8 ones;
#pragma unroll
    for (int e = 0; e < 8; ++e) ones[e] = (half_t)(lr == 0 ? 1.0f : 0.0f);

    auto LOAD = [&](int jb, f16x8* bfr, f32x4& e2a, f32x4& e2b, f32x4& f2a, f32x4& f2b,
                    uint32_t* bw) {
        const int jk = jb + kg * 8;
        const int jc = jb >> 5;
        e2a = *(const f32x4*)(E2p + jk);
        e2b = *(const f32x4*)(E2p + jk + 4);
        f2a = *(const f32x4*)(F2p + jk);
        f2b = *(const f32x4*)(F2p + jk + 4);
        const half_t* vb = VTt + (size_t)jc * TS + kg * 8;
#pragma unroll
        for (int dt = 0; dt < 4; ++dt)
            bfr[dt] = *(const f16x8*)(vb + (size_t)(cb + dt * 16 + lr) * 32);
        const uint32_t* bb = bitsT + (size_t)jc * NN + rowb;
#pragma unroll
        for (int rt = 0; rt < 4; ++rt)
            bw[rt] = bb[rt * 16 + lr];
    };
    auto COMP = [&](const f16x8* bfr, f32x4 e2a, f32x4 e2b, f32x4 f2a, f32x4 f2b,
                    const uint32_t* bw) {
#pragma unroll
        for (int rt = 0; rt < 4; ++rt) {
            uint32_t mb = (bw[rt] >> (kg * 8)) & 0xffu;
            f16x8 af;
#pragma unroll
            for (int e = 0; e < 8; ++e) {
                float e2 = (e < 4) ? e2a[e] : e2b[e - 4];
                float f2 = (e < 4) ? f2a[e] : f2b[e - 4];
                float p = fmaxf(e2, gv[rt] * f2);
                p = (mb & (1u << e)) ? p : 0.0f;
                af[e] = (half_t)p;
            }
#pragma unroll
            for (int dt = 0; dt < 4; ++dt)
                acc[rt][dt] = __builtin_amdgcn_mfma_f32_16x16x32_f16(af, bfr[dt], acc[rt][dt], 0, 0, 0);
            accz[rt] = __builtin_amdgcn_mfma_f32_16x16x32_f16(af, ones, accz[rt], 0, 0, 0);
        }
    };

    f16x8 bA[4], bB[4];
    f32x4 eaA, ebA, faA, fbA, eaB, ebB, faB, fbB;
    uint32_t wA[4], wB[4];
    LOAD(jb0, bA, eaA, ebA, faA, fbA, wA);
    for (int js = 0; js < steps - 2; js += 2) {
        LOAD(jb0 + (js + 1) * 32, bB, eaB, ebB, faB, fbB, wB);
        COMP(bA, eaA, ebA, faA, fbA, wA);
        LOAD(jb0 + (js + 2) * 32, bA, eaA, ebA, faA, fbA, wA);
        COMP(bB, eaB, ebB, faB, fbB, wB);
    }
    LOAD(jb0 + (steps - 1) * 32, bB, eaB, ebB, faB, fbB, wB);
    COMP(bA, eaA, ebA, faA, fbA, wA);
    COMP(bB, eaB, ebB, faB, fbB, wB);

    bf16_t* Hp = Hpart + (size_t)jz * NN * CT;
#pragma unroll
    for (int rt = 0; rt < 4; ++rt) {
#pragma unroll
        for (int dt = 0; dt < 4; ++dt)
#pragma unroll
            for (int r = 0; r < 4; ++r)
                Hp[(size_t)(rowb + rt * 16 + kg * 4 + r) * CT + cb + dt * 16 + lr] = (bf16_t)acc[rt][dt][r];
    }
    if (lr == 0 && (ZC > 1 || c == 0)) {
        int zi = jz * ZC + (ZC > 1 ? c : 0);
#pragma unroll
        for (int rt = 0; rt < 4; ++rt)
#pragma unroll
            for (int r = 0; r < 4; ++r)
                zpart[(size_t)zi * NN + rowb + rt * 16 + kg * 4 + r] = accz[rt][r];
    }
}

// ---- finalize layer 1: hcatb = bf16(ELU(sum H / sum Z)), 8 cols/thread
__global__ __launch_bounds__(256) void fin1_k(const bf16_t* __restrict__ Hpart,
                                              const float* __restrict__ zpart,
                                              bf16_t* __restrict__ hcatb) {
    int idx = blockIdx.x * 256 + threadIdx.x;   // < N*64
    int i = idx >> 6, col0 = (idx & 63) << 3, h = col0 >> 6;
    float Z = 0.f;
#pragma unroll
    for (int jz = 0; jz < 8; ++jz) Z += zpart[(size_t)(jz * 8 + h) * NN + i];
    float hs[8];
#pragma unroll
    for (int e = 0; e < 8; ++e) hs[e] = 0.f;
#pragma unroll
    for (int jz = 0; jz < 8; ++jz) {
        bf16x8 v = *(const bf16x8*)(Hpart + ((size_t)jz * NN + i) * 512 + col0);
#pragma unroll
        for (int e = 0; e < 8; ++e) hs[e] += (float)v[e];
    }
    float invZ = 1.0f / Z;
    bf16x8 o;
#pragma unroll
    for (int e = 0; e < 8; ++e) {
        float v = hs[e] * invZ;
        o[e] = (bf16_t)(v > 0.f ? v : expm1f(v));
    }
    *(bf16x8*)(hcatb + (size_t)i * 512 + col0) = o;
}

// ---- combine split-K gemm2 slices: VT2t (j-tiled f16) + g/E2/F2. 128thr=1 row.
__global__ __launch_bounds__(128) void comb2_k(const float* __restrict__ Cp,
                                               const float* __restrict__ a1o,
                                               const float* __restrict__ a2o,
                                               half_t* __restrict__ VT2t,
                                               float* __restrict__ g1o,
                                               float* __restrict__ E2o,
                                               float* __restrict__ F2o) {
    int r = blockIdx.x, t = threadIdx.x;
    float w = 0.f;
#pragma unroll
    for (int z = 0; z < 4; ++z) w += Cp[((size_t)z * NN + r) * 128 + t];
    VT2t[(size_t)(r >> 5) * (128 * 32) + t * 32 + (r & 31)] = (half_t)w;
    float d1 = w * a1o[t], d2 = w * a2o[t];
#pragma unroll
    for (int o = 1; o < 64; o <<= 1) { d1 += __shfl_xor(d1, o); d2 += __shfl_xor(d2, o); }
    __shared__ float red[4];
    if ((t & 63) == 0) { red[(t >> 6) * 2 + 0] = d1; red[(t >> 6) * 2 + 1] = d2; }
    __syncthreads();
    if (t == 0) {
        float s1 = red[0] + red[2], s2 = red[1] + red[3];
        g1o[r] = exp2f(-0.8f * LOG2E * s1);
        E2o[r] = exp2f(LOG2E * s2);
        F2o[r] = exp2f(0.2f * LOG2E * s2);
    }
}

// ---- finalize layer 2: out fp32 = sum H / sum Z, 8 cols/thread
__global__ __launch_bounds__(256) void fin2_k(const bf16_t* __restrict__ Hpart,
                                              const float* __restrict__ zpart,
                                              float* __restrict__ out) {
    int idx = blockIdx.x * 256 + threadIdx.x;   // < N*16
    int i = idx >> 4, col0 = (idx & 15) << 3;
    float Z = 0.f;
#pragma unroll
    for (int jz = 0; jz < 16; ++jz) Z += zpart[(size_t)jz * NN + i];
    float hs[8];
#pragma unroll
    for (int e = 0; e < 8; ++e) hs[e] = 0.f;
#pragma unroll
    for (int jz = 0; jz < 16; ++jz) {
        bf16x8 v = *(const bf16x8*)(Hpart + ((size_t)jz * NN + i) * 128 + col0);
#pragma unroll
        for (int e = 0; e < 8; ++e) hs[e] += (float)v[e];
    }
    float invZ = 1.0f / Z;
    f32x4 o0, o1;
#pragma unroll
    for (int e = 0; e < 4; ++e) { o0[e] = hs[e] * invZ; o1[e] = hs[e + 4] * invZ; }
    *(f32x4*)(out + (size_t)i * 128 + col0) = o0;
    *(f32x4*)(out + (size_t)i * 128 + col0 + 4) = o1;
}

extern "C" void kernel_launch(void* const* d_in, const int* in_sizes, int n_in,
                              void* d_out, int out_size, void* d_ws, size_t ws_size,
                              hipStream_t stream) {
    const int N = 4096;
    const float* x       = (const float*)d_in[0];
    const int*   adj     = (const int*)d_in[1];
    const float* W_heads = (const float*)d_in[2];
    const float* a1h     = (const float*)d_in[3];
    const float* a2h     = (const float*)d_in[4];
    const float* W_out   = (const float*)d_in[5];
    const float* a1o     = (const float*)d_in[6];
    const float* a2o     = (const float*)d_in[7];
    (void)in_sizes; (void)n_in; (void)out_size; (void)ws_size;

    size_t off = 0;
    auto alloc = [&](size_t bytes) { size_t o = off; off = (off + bytes + 255) & ~(size_t)255; return o; };
    char* ws = (char*)d_ws;
    uint32_t* bitsT = (uint32_t*)(ws + alloc((size_t)N * N / 8));        // 2 MB
    half_t* VT1t    = (half_t*)(ws + alloc((size_t)512 * N * 2));        // 4 MB (j-tiled f16)
    bf16_t* hcatb   = (bf16_t*)(ws + alloc((size_t)N * 512 * 2));        // 4 MB
    bf16_t* WoutT   = (bf16_t*)(ws + alloc((size_t)128 * 512 * 2));      // 128 KB
    float*  g1h     = (float*)(ws + alloc((size_t)8 * N * 4));
    float*  E2h     = (float*)(ws + alloc((size_t)8 * N * 4));
    float*  F2h     = (float*)(ws + alloc((size_t)8 * N * 4));
    float*  g1o     = (float*)(ws + alloc((size_t)N * 4));
    float*  E2o     = (float*)(ws + alloc((size_t)N * 4));
    float*  F2o     = (float*)(ws + alloc((size_t)N * 4));
    half_t* VT2t    = (half_t*)(ws + alloc((size_t)128 * N * 2));        // 1 MB (j-tiled f16)
    float*  zpart   = (float*)(ws + alloc((size_t)64 * N * 4));          // 1 MB
    bf16_t* Hpart   = (bf16_t*)(ws + alloc((size_t)32 * 1024 * 1024));   // 32 MB
    // aliases into the Hpart region (temporally disjoint):
    bf16_t* xbt   = (bf16_t*)Hpart;                       // 4 MB, dead after gemm1
    bf16_t* WT1t  = (bf16_t*)((char*)Hpart + (9 << 20));  // 0.5 MB, dead after gemm1
    float*  Cpart = (float*)Hpart;                        // gemm2..comb2 only

    // 1. adjacency bitmask (transposed)
    hipLaunchKernelGGL(pack_bits_k, dim3(2048), dim3(256), 0, stream, adj, bitsT, N * N);
    // 2. prep: K-tiled bf16 xbt/WT1t + row-major WoutT
    hipLaunchKernelGGL(prep_k, dim3(1024), dim3(256), 0, stream, x, W_heads, W_out, xbt, WT1t, WoutT);
    // 3. gemm1 (TILED inputs): VT1t (f16) + g/E2/F2 per head
    hipLaunchKernelGGL((gemm_k<1, 0, 1>), dim3(64, 8, 1), dim3(256), 0, stream,
                       xbt, WT1t, VT1t, (float*)nullptr, a1h, a2h, g1h, E2h, F2h, 512, 512, 512, 512);
    // 4. layer-1 aggregate: 8-wave blocks, grid x=head(8), y=rowtile(64); jz=wave 0..7
    hipLaunchKernelGGL((gat_agg_k<8, 1>), dim3(8, 64, 1), dim3(512), 0, stream,
                       g1h, E2h, F2h, N, bitsT, VT1t, Hpart, zpart, 512, 512, 8, 512 * 32);
    // 5. finalize 1 -> hcatb
    hipLaunchKernelGGL(fin1_k, dim3(1024), dim3(256), 0, stream, Hpart, zpart, hcatb);
    // 6. gemm2 split-K=4 (row-major inputs) -> Cpart
    hipLaunchKernelGGL((gemm_k<0, 1, 0>), dim3(64, 2, 4), dim3(256), 0, stream,
                       hcatb, WoutT, (half_t*)nullptr, Cpart,
                       (const float*)nullptr, (const float*)nullptr,
                       (float*)nullptr, (float*)nullptr, (float*)nullptr, 512, 128, 128, 128);
    // 7. combine -> VT2t (f16), g1o/E2o/F2o
    hipLaunchKernelGGL(comb2_k, dim3(4096), dim3(128), 0, stream, Cpart, a1o, a2o, VT2t, g1o, E2o, F2o);
    // 8. layer-2 aggregate: 4-wave blocks, grid x=(c,jzgrp)=8, y=rowtile(64)
    hipLaunchKernelGGL((gat_agg_k<4, 4>), dim3(8, 64, 1), dim3(256), 0, stream,
                       g1o, E2o, F2o, 0, bitsT, VT2t, Hpart, zpart, 128, 256, 1, 128 * 32);
    // 9. finalize 2 -> out
    hipLaunchKernelGGL(fin2_k, dim3(256), dim3(256), 0, stream, Hpart, zpart, (float*)d_out);
}

// Round 18
// 133.268 us; speedup vs baseline: 1.0592x; 1.0382x over previous
//
#include <hip/hip_runtime.h>
#include <hip/hip_bf16.h>
#include <cstdint>

// ---------------------------------------------------------------------------
// GAT forward, N=4096, F=512, D=64, H=8, O=128, fp32 in/out.
// Identity: exp(lrelu(u)) = max(exp(u), exp(0.2u)); u = s1_i+s2_j rank-1;
// softmax row-scale invariance => p'_ij = max(E2_j, g_i*F2_j), g=exp(-0.8 s1).
// Round-18 = Round-14 (best: 136.5us; agg1 47.0; NW=4, JR=1024, 4-plane
// Hpart) + fused prep: adjacency bit-packing (ballot-free, 1 word/thread,
// int4 reads) merged into the conversion/transpose kernel -> one fewer
// launch, overlapped HBM streams. Agg inner loop byte-identical to R14.
// ---------------------------------------------------------------------------

using bf16_t = __bf16;
using half_t = _Float16;
using bf16x4 = __attribute__((ext_vector_type(4))) __bf16;
using bf16x8 = __attribute__((ext_vector_type(8))) __bf16;
using f16x4  = __attribute__((ext_vector_type(4))) _Float16;
using f16x8  = __attribute__((ext_vector_type(8))) _Float16;
using f32x4  = __attribute__((ext_vector_type(4))) float;

#define LOG2E 1.44269504f
constexpr int NN = 4096;

// ---- fused prep: adjacency -> transposed bitmask (1 word/thread),
//      x -> xbt (K-tiled bf16 [kc][4096][32]), W_heads -> WT1t ([kc][512][32]),
//      W_out -> WoutT[o][512] row-major.
__global__ __launch_bounds__(256) void prep_k(const int* __restrict__ adj,
                                              const float* __restrict__ x,
                                              const float* __restrict__ Wh,
                                              const float* __restrict__ Wo,
                                              uint32_t* __restrict__ bitsT,
                                              bf16_t* __restrict__ xbt,
                                              bf16_t* __restrict__ WT1t,
                                              bf16_t* __restrict__ WoutT) {
    const int NB  = NN * NN / 32;        // 524288 bitsT words
    const int NXT = NN * 512 / 8;        // 262144 xbt groups
    const int NWT = 512 * 512 / 8;       // 32768 WT1t groups
    const int NW2 = 128 * 512;           // 65536 WoutT scalars
    int stride = gridDim.x * blockDim.x;
    for (int t = blockIdx.x * blockDim.x + threadIdx.x; t < NB + NXT + NWT + NW2; t += stride) {
        if (t < NB) {
            // word w = (jc, i): bitsT[jc*N + i] = bits of adj[i][jc*32..+31]
            int jc = t >> 12, i = t & 4095;
            const int4* ap = (const int4*)(adj + (size_t)i * NN + jc * 32);
            uint32_t w = 0;
#pragma unroll
            for (int q = 0; q < 8; ++q) {
                int4 a = ap[q];
                w |= (a.x > 0 ? 1u : 0u) << (q * 4 + 0);
                w |= (a.y > 0 ? 1u : 0u) << (q * 4 + 1);
                w |= (a.z > 0 ? 1u : 0u) << (q * 4 + 2);
                w |= (a.w > 0 ? 1u : 0u) << (q * 4 + 3);
            }
            bitsT[t] = w;
        } else if (t < NB + NXT) {
            size_t d = (size_t)(t - NB) * 8;
            int kc = (int)(d >> 17);
            int rem = (int)(d & 131071);
            int i = rem >> 5, k0 = rem & 31;
            const float* sp = x + (size_t)i * 512 + kc * 32 + k0;
            f32x4 s0 = *(const f32x4*)sp;
            f32x4 s1 = *(const f32x4*)(sp + 4);
            bf16x8 o;
#pragma unroll
            for (int e = 0; e < 4; ++e) { o[e] = (bf16_t)s0[e]; o[4 + e] = (bf16_t)s1[e]; }
            *(bf16x8*)(xbt + d) = o;
        } else if (t < NB + NXT + NWT) {
            size_t d = (size_t)(t - NB - NXT) * 8;
            int kc = (int)(d >> 14);
            int rem = (int)(d & 16383);
            int col = rem >> 5, k0 = rem & 31;
            int h = col >> 6, dd = col & 63;
            bf16x8 o;
#pragma unroll
            for (int e = 0; e < 8; ++e)
                o[e] = (bf16_t)Wh[(size_t)(h << 15) + (size_t)(kc * 32 + k0 + e) * 64 + dd];
            *(bf16x8*)(WT1t + d) = o;
        } else {
            int u = t - NB - NXT - NWT;
            int o2 = u >> 9, cc = u & 511;
            WoutT[u] = (bf16_t)Wo[cc * 128 + o2];
        }
    }
}

// ---- bf16 MFMA GEMM, 4 waves/block, wave = 16 rows x 64 cols.
// TILED=1: A/B read K-tiled [kc][row|col][32]; TILED=0: row-major (gemm2).
// CS: epilogue writes VTt as F16 (j-tiled [i>>5][col][i&31]) + g/E2/F2.
// WC: writes fp32 partial C slice (split-K via blockIdx.z)
template<int CS, int WC, int TILED>
__global__ __launch_bounds__(256) void gemm_k(const bf16_t* __restrict__ A,
                                              const bf16_t* __restrict__ BT,
                                              half_t* __restrict__ VTt,
                                              float* __restrict__ Cp,
                                              const float* __restrict__ a1,
                                              const float* __restrict__ a2,
                                              float* __restrict__ g1,
                                              float* __restrict__ E2,
                                              float* __restrict__ F2,
                                              int K, int NC, int kslice, int NCOLS) {
    const int wave = threadIdx.x >> 6, lane = threadIdx.x & 63;
    const int lr = lane & 15, kg = lane >> 4;
    const int rowb = (blockIdx.x * 4 + wave) * 16, cb = blockIdx.y * 64, kz = blockIdx.z;
    f32x4 acc[4];
#pragma unroll
    for (int dt = 0; dt < 4; ++dt) acc[dt] = 0.0f;
    const int k0beg = kz * kslice, k0end = k0beg + kslice;
    for (int k0 = k0beg; k0 < k0end; k0 += 32) {
        bf16x8 af;
        if (TILED) {
            const int kc = k0 >> 5;
            af = *(const bf16x8*)(A + (size_t)kc * (NN * 32) + (size_t)(rowb + lr) * 32 + kg * 8);
        } else {
            af = *(const bf16x8*)(A + (size_t)(rowb + lr) * K + k0 + kg * 8);
        }
#pragma unroll
        for (int dt = 0; dt < 4; ++dt) {
            bf16x8 bfr;
            if (TILED) {
                const int kc = k0 >> 5;
                bfr = *(const bf16x8*)(BT + (size_t)kc * (NC * 32) +
                                       (size_t)(cb + dt * 16 + lr) * 32 + kg * 8);
            } else {
                bfr = *(const bf16x8*)(BT + (size_t)(cb + dt * 16 + lr) * K + k0 + kg * 8);
            }
            acc[dt] = __builtin_amdgcn_mfma_f32_16x16x32_bf16(af, bfr, acc[dt], 0, 0, 0);
        }
    }
    if (WC) {
#pragma unroll
        for (int dt = 0; dt < 4; ++dt)
#pragma unroll
            for (int r = 0; r < 4; ++r)
                Cp[((size_t)kz * NN + rowb + kg * 4 + r) * NC + cb + dt * 16 + lr] = acc[dt][r];
    }
    if (CS) {
        const int i0 = rowb + kg * 4;
        const size_t tbase = (size_t)(i0 >> 5) * NCOLS * 32 + (i0 & 31);
#pragma unroll
        for (int dt = 0; dt < 4; ++dt) {
            f16x4 v;
#pragma unroll
            for (int r = 0; r < 4; ++r) v[r] = (half_t)acc[dt][r];
            *(f16x4*)(VTt + tbase + (size_t)(cb + dt * 16 + lr) * 32) = v;
        }
        float a1v[4], a2v[4];
#pragma unroll
        for (int dt = 0; dt < 4; ++dt) {
            a1v[dt] = a1[cb + dt * 16 + lr];
            a2v[dt] = a2[cb + dt * 16 + lr];
        }
#pragma unroll
        for (int r = 0; r < 4; ++r) {
            float d1 = 0.f, d2 = 0.f;
#pragma unroll
            for (int dt = 0; dt < 4; ++dt) { d1 += acc[dt][r] * a1v[dt]; d2 += acc[dt][r] * a2v[dt]; }
#pragma unroll
            for (int o = 1; o < 16; o <<= 1) { d1 += __shfl_xor(d1, o); d2 += __shfl_xor(d2, o); }
            if (lr == 0) {
                size_t row = (size_t)blockIdx.y * NN + rowb + kg * 4 + r;
                g1[row] = exp2f(-0.8f * LOG2E * d1);
                E2[row] = exp2f(LOG2E * d2);
                F2[row] = exp2f(0.2f * LOG2E * d2);
            }
        }
    }
}

// ---- fused attention-aggregate (R14 inner loop, NW waves/block).
// grid = (CG*JZG, 64); x -> (c = x/JZG, jzg = x%JZG); y = rowtile.
// NW waves/block; wave w owns jz = jzg*NW + w; wave = 64 rows x 64 cols.
// p'_ij = adj ? max(E2_j, g_i*F2_j) : 0  (f32 math, cvt f16, cndmask mask).
// Z row-sums via extra f16 MFMA against a ones-column B-fragment.
template<int NW, int JZG>
__global__ __launch_bounds__(64 * NW) void gat_agg_k(const float* __restrict__ g1,
                                                     const float* __restrict__ E2,
                                                     const float* __restrict__ F2, int shead,
                                                     const uint32_t* __restrict__ bitsT,
                                                     const half_t* __restrict__ VTt,
                                                     bf16_t* __restrict__ Hpart,
                                                     float* __restrict__ zpart,
                                                     int CT, int JR, int ZC, int TS) {
    const int wave = threadIdx.x >> 6, lane = threadIdx.x & 63;
    const int lr = lane & 15, kg = lane >> 4;
    const int c = blockIdx.x / JZG, jzg = blockIdx.x % JZG;
    const int rowb = blockIdx.y * 64;
    const int jz = jzg * NW + wave;
    const int cb = c * 64;
    const float* gp  = g1 + (size_t)shead * c;
    const float* E2p = E2 + (size_t)shead * c;
    const float* F2p = F2 + (size_t)shead * c;
    const int steps = JR >> 5, jb0 = jz * JR;

    f32x4 acc[4][4], accz[4];
#pragma unroll
    for (int rt = 0; rt < 4; ++rt) {
        accz[rt] = 0.0f;
#pragma unroll
        for (int dt = 0; dt < 4; ++dt) acc[rt][dt] = 0.0f;
    }
    float gv[4];
#pragma unroll
    for (int rt = 0; rt < 4; ++rt) gv[rt] = gp[rowb + rt * 16 + lr];
    f16x8 ones;
#pragma unroll
    for (int e = 0; e < 8; ++e) ones[e] = (half_t)(lr == 0 ? 1.0f : 0.0f);

    auto LOAD = [&](int jb, f16x8* bfr, f32x4& e2a, f32x4& e2b, f32x4& f2a, f32x4& f2b,
                    uint32_t* bw) {
        const int jk = jb + kg * 8;
        const int jc = jb >> 5;
        e2a = *(const f32x4*)(E2p + jk);
        e2b = *(const f32x4*)(E2p + jk + 4);
        f2a = *(const f32x4*)(F2p + jk);
        f2b = *(const f32x4*)(F2p + jk + 4);
        const half_t* vb = VTt + (size_t)jc * TS + kg * 8;
#pragma unroll
        for (int dt = 0; dt < 4; ++dt)
            bfr[dt] = *(const f16x8*)(vb + (size_t)(cb + dt * 16 + lr) * 32);
        const uint32_t* bb = bitsT + (size_t)jc * NN + rowb;
#pragma unroll
        for (int rt = 0; rt < 4; ++rt)
            bw[rt] = bb[rt * 16 + lr];
    };
    auto COMP = [&](const f16x8* bfr, f32x4 e2a, f32x4 e2b, f32x4 f2a, f32x4 f2b,
                    const uint32_t* bw) {
#pragma unroll
        for (int rt = 0; rt < 4; ++rt) {
            uint32_t mb = (bw[rt] >> (kg * 8)) & 0xffu;
            f16x8 af;
#pragma unroll
            for (int e = 0; e < 8; ++e) {
                float e2 = (e < 4) ? e2a[e] : e2b[e - 4];
                float f2 = (e < 4) ? f2a[e] : f2b[e - 4];
                float p = fmaxf(e2, gv[rt] * f2);
                p = (mb & (1u << e)) ? p : 0.0f;
                af[e] = (half_t)p;
            }
#pragma unroll
            for (int dt = 0; dt < 4; ++dt)
                acc[rt][dt] = __builtin_amdgcn_mfma_f32_16x16x32_f16(af, bfr[dt], acc[rt][dt], 0, 0, 0);
            accz[rt] = __builtin_amdgcn_mfma_f32_16x16x32_f16(af, ones, accz[rt], 0, 0, 0);
        }
    };

    f16x8 bA[4], bB[4];
    f32x4 eaA, ebA, faA, fbA, eaB, ebB, faB, fbB;
    uint32_t wA[4], wB[4];
    LOAD(jb0, bA, eaA, ebA, faA, fbA, wA);
    for (int js = 0; js < steps - 2; js += 2) {
        LOAD(jb0 + (js + 1) * 32, bB, eaB, ebB, faB, fbB, wB);
        COMP(bA, eaA, ebA, faA, fbA, wA);
        LOAD(jb0 + (js + 2) * 32, bA, eaA, ebA, faA, fbA, wA);
        COMP(bB, eaB, ebB, faB, fbB, wB);
    }
    LOAD(jb0 + (steps - 1) * 32, bB, eaB, ebB, faB, fbB, wB);
    COMP(bA, eaA, ebA, faA, fbA, wA);
    COMP(bB, eaB, ebB, faB, fbB, wB);

    bf16_t* Hp = Hpart + (size_t)jz * NN * CT;
#pragma unroll
    for (int rt = 0; rt < 4; ++rt) {
#pragma unroll
        for (int dt = 0; dt < 4; ++dt)
#pragma unroll
            for (int r = 0; r < 4; ++r)
                Hp[(size_t)(rowb + rt * 16 + kg * 4 + r) * CT + cb + dt * 16 + lr] = (bf16_t)acc[rt][dt][r];
    }
    if (lr == 0 && (ZC > 1 || c == 0)) {
        int zi = jz * ZC + (ZC > 1 ? c : 0);
#pragma unroll
        for (int rt = 0; rt < 4; ++rt)
#pragma unroll
            for (int r = 0; r < 4; ++r)
                zpart[(size_t)zi * NN + rowb + rt * 16 + kg * 4 + r] = accz[rt][r];
    }
}

// ---- finalize layer 1: hcatb = bf16(ELU(sum H / sum Z)), 8 cols/thread
__global__ __launch_bounds__(256) void fin1_k(const bf16_t* __restrict__ Hpart,
                                              const float* __restrict__ zpart,
                                              bf16_t* __restrict__ hcatb) {
    int idx = blockIdx.x * 256 + threadIdx.x;   // < N*64
    int i = idx >> 6, col0 = (idx & 63) << 3, h = col0 >> 6;
    float Z = 0.f;
#pragma unroll
    for (int jz = 0; jz < 4; ++jz) Z += zpart[(size_t)(jz * 8 + h) * NN + i];
    float hs[8];
#pragma unroll
    for (int e = 0; e < 8; ++e) hs[e] = 0.f;
#pragma unroll
    for (int jz = 0; jz < 4; ++jz) {
        bf16x8 v = *(const bf16x8*)(Hpart + ((size_t)jz * NN + i) * 512 + col0);
#pragma unroll
        for (int e = 0; e < 8; ++e) hs[e] += (float)v[e];
    }
    float invZ = 1.0f / Z;
    bf16x8 o;
#pragma unroll
    for (int e = 0; e < 8; ++e) {
        float v = hs[e] * invZ;
        o[e] = (bf16_t)(v > 0.f ? v : expm1f(v));
    }
    *(bf16x8*)(hcatb + (size_t)i * 512 + col0) = o;
}

// ---- combine split-K gemm2 slices: VT2t (j-tiled f16) + g/E2/F2. 128thr=1 row.
__global__ __launch_bounds__(128) void comb2_k(const float* __restrict__ Cp,
                                               const float* __restrict__ a1o,
                                               const float* __restrict__ a2o,
                                               half_t* __restrict__ VT2t,
                                               float* __restrict__ g1o,
                                               float* __restrict__ E2o,
                                               float* __restrict__ F2o) {
    int r = blockIdx.x, t = threadIdx.x;
    float w = 0.f;
#pragma unroll
    for (int z = 0; z < 4; ++z) w += Cp[((size_t)z * NN + r) * 128 + t];
    VT2t[(size_t)(r >> 5) * (128 * 32) + t * 32 + (r & 31)] = (half_t)w;
    float d1 = w * a1o[t], d2 = w * a2o[t];
#pragma unroll
    for (int o = 1; o < 64; o <<= 1) { d1 += __shfl_xor(d1, o); d2 += __shfl_xor(d2, o); }
    __shared__ float red[4];
    if ((t & 63) == 0) { red[(t >> 6) * 2 + 0] = d1; red[(t >> 6) * 2 + 1] = d2; }
    __syncthreads();
    if (t == 0) {
        float s1 = red[0] + red[2], s2 = red[1] + red[3];
        g1o[r] = exp2f(-0.8f * LOG2E * s1);
        E2o[r] = exp2f(LOG2E * s2);
        F2o[r] = exp2f(0.2f * LOG2E * s2);
    }
}

// ---- finalize layer 2: out fp32 = sum H / sum Z, 8 cols/thread
__global__ __launch_bounds__(256) void fin2_k(const bf16_t* __restrict__ Hpart,
                                              const float* __restrict__ zpart,
                                              float* __restrict__ out) {
    int idx = blockIdx.x * 256 + threadIdx.x;   // < N*16
    int i = idx >> 4, col0 = (idx & 15) << 3;
    float Z = 0.f;
#pragma unroll
    for (int jz = 0; jz < 16; ++jz) Z += zpart[(size_t)jz * NN + i];
    float hs[8];
#pragma unroll
    for (int e = 0; e < 8; ++e) hs[e] = 0.f;
#pragma unroll
    for (int jz = 0; jz < 16; ++jz) {
        bf16x8 v = *(const bf16x8*)(Hpart + ((size_t)jz * NN + i) * 128 + col0);
#pragma unroll
        for (int e = 0; e < 8; ++e) hs[e] += (float)v[e];
    }
    float invZ = 1.0f / Z;
    f32x4 o0, o1;
#pragma unroll
    for (int e = 0; e < 4; ++e) { o0[e] = hs[e] * invZ; o1[e] = hs[e + 4] * invZ; }
    *(f32x4*)(out + (size_t)i * 128 + col0) = o0;
    *(f32x4*)(out + (size_t)i * 128 + col0 + 4) = o1;
}

extern "C" void kernel_launch(void* const* d_in, const int* in_sizes, int n_in,
                              void* d_out, int out_size, void* d_ws, size_t ws_size,
                              hipStream_t stream) {
    const int N = 4096;
    const float* x       = (const float*)d_in[0];
    const int*   adj     = (const int*)d_in[1];
    const float* W_heads = (const float*)d_in[2];
    const float* a1h     = (const float*)d_in[3];
    const float* a2h     = (const float*)d_in[4];
    const float* W_out   = (const float*)d_in[5];
    const float* a1o     = (const float*)d_in[6];
    const float* a2o     = (const float*)d_in[7];
    (void)in_sizes; (void)n_in; (void)out_size; (void)ws_size;

    size_t off = 0;
    auto alloc = [&](size_t bytes) { size_t o = off; off = (off + bytes + 255) & ~(size_t)255; return o; };
    char* ws = (char*)d_ws;
    uint32_t* bitsT = (uint32_t*)(ws + alloc((size_t)N * N / 8));        // 2 MB
    half_t* VT1t    = (half_t*)(ws + alloc((size_t)512 * N * 2));        // 4 MB (j-tiled f16)
    bf16_t* hcatb   = (bf16_t*)(ws + alloc((size_t)N * 512 * 2));        // 4 MB
    bf16_t* WoutT   = (bf16_t*)(ws + alloc((size_t)128 * 512 * 2));      // 128 KB
    float*  g1h     = (float*)(ws + alloc((size_t)8 * N * 4));
    float*  E2h     = (float*)(ws + alloc((size_t)8 * N * 4));
    float*  F2h     = (float*)(ws + alloc((size_t)8 * N * 4));
    float*  g1o     = (float*)(ws + alloc((size_t)N * 4));
    float*  E2o     = (float*)(ws + alloc((size_t)N * 4));
    float*  F2o     = (float*)(ws + alloc((size_t)N * 4));
    half_t* VT2t    = (half_t*)(ws + alloc((size_t)128 * N * 2));        // 1 MB (j-tiled f16)
    float*  zpart   = (float*)(ws + alloc((size_t)64 * N * 4));          // 1 MB
    bf16_t* Hpart   = (bf16_t*)(ws + alloc((size_t)32 * 1024 * 1024));   // 32 MB (16 used L1)
    // aliases into the Hpart region (temporally disjoint):
    bf16_t* xbt   = (bf16_t*)Hpart;                       // 4 MB, dead after gemm1
    bf16_t* WT1t  = (bf16_t*)((char*)Hpart + (9 << 20));  // 0.5 MB, dead after gemm1
    float*  Cpart = (float*)Hpart;                        // gemm2..comb2 only

    // 1. fused prep: bitsT + K-tiled bf16 xbt/WT1t + row-major WoutT
    hipLaunchKernelGGL(prep_k, dim3(2048), dim3(256), 0, stream,
                       adj, x, W_heads, W_out, bitsT, xbt, WT1t, WoutT);
    // 2. gemm1 (TILED inputs): VT1t (f16) + g/E2/F2 per head
    hipLaunchKernelGGL((gemm_k<1, 0, 1>), dim3(64, 8, 1), dim3(256), 0, stream,
                       xbt, WT1t, VT1t, (float*)nullptr, a1h, a2h, g1h, E2h, F2h, 512, 512, 512, 512);
    // 3. layer-1 aggregate: 4-wave blocks, grid x=head(8), y=rowtile(64); jz=wave 0..3, JR=1024
    hipLaunchKernelGGL((gat_agg_k<4, 1>), dim3(8, 64, 1), dim3(256), 0, stream,
                       g1h, E2h, F2h, N, bitsT, VT1t, Hpart, zpart, 512, 1024, 8, 512 * 32);
    // 4. finalize 1 -> hcatb
    hipLaunchKernelGGL(fin1_k, dim3(1024), dim3(256), 0, stream, Hpart, zpart, hcatb);
    // 5. gemm2 split-K=4 (row-major inputs) -> Cpart
    hipLaunchKernelGGL((gemm_k<0, 1, 0>), dim3(64, 2, 4), dim3(256), 0, stream,
                       hcatb, WoutT, (half_t*)nullptr, Cpart,
                       (const float*)nullptr, (const float*)nullptr,
                       (float*)nullptr, (float*)nullptr, (float*)nullptr, 512, 128, 128, 128);
    // 6. combine -> VT2t (f16), g1o/E2o/F2o
    hipLaunchKernelGGL(comb2_k, dim3(4096), dim3(128), 0, stream, Cpart, a1o, a2o, VT2t, g1o, E2o, F2o);
    // 7. layer-2 aggregate: 4-wave blocks, grid x=(c,jzgrp)=8, y=rowtile(64); JR=256
    hipLaunchKernelGGL((gat_agg_k<4, 4>), dim3(8, 64, 1), dim3(256), 0, stream,
                       g1o, E2o, F2o, 0, bitsT, VT2t, Hpart, zpart, 128, 256, 1, 128 * 32);
    // 8. finalize 2 -> out
    hipLaunchKernelGGL(fin2_k, dim3(256), dim3(256), 0, stream, Hpart, zpart, (float*)d_out);
}

// Round 19
// 121.728 us; speedup vs baseline: 1.1597x; 1.0948x over previous
//
#include <hip/hip_runtime.h>
#include <hip/hip_bf16.h>
#include <cstdint>

// ---------------------------------------------------------------------------
// GAT forward, N=4096, F=512, D=64, H=8, O=128, fp32 in/out.
// Identity: exp(lrelu(u)) = max(exp(u), exp(0.2u)); u = s1_i+s2_j rank-1;
// softmax row-scale invariance => p'_ij = max(E2_j, g_i*F2_j), g=exp(-0.8 s1).
// Round-19 = Round-18 (best: 133.3us) + gemm1 RT=2 (32 rows/wave): halves
// B-fragment re-reads + addressing per output. Everything else identical.
// ---------------------------------------------------------------------------

using bf16_t = __bf16;
using half_t = _Float16;
using bf16x4 = __attribute__((ext_vector_type(4))) __bf16;
using bf16x8 = __attribute__((ext_vector_type(8))) __bf16;
using f16x4  = __attribute__((ext_vector_type(4))) _Float16;
using f16x8  = __attribute__((ext_vector_type(8))) _Float16;
using f32x4  = __attribute__((ext_vector_type(4))) float;

#define LOG2E 1.44269504f
constexpr int NN = 4096;

// ---- fused prep: adjacency -> transposed bitmask (1 word/thread),
//      x -> xbt (K-tiled bf16 [kc][4096][32]), W_heads -> WT1t ([kc][512][32]),
//      W_out -> WoutT[o][512] row-major.
__global__ __launch_bounds__(256) void prep_k(const int* __restrict__ adj,
                                              const float* __restrict__ x,
                                              const float* __restrict__ Wh,
                                              const float* __restrict__ Wo,
                                              uint32_t* __restrict__ bitsT,
                                              bf16_t* __restrict__ xbt,
                                              bf16_t* __restrict__ WT1t,
                                              bf16_t* __restrict__ WoutT) {
    const int NB  = NN * NN / 32;
    const int NXT = NN * 512 / 8;
    const int NWT = 512 * 512 / 8;
    const int NW2 = 128 * 512;
    int stride = gridDim.x * blockDim.x;
    for (int t = blockIdx.x * blockDim.x + threadIdx.x; t < NB + NXT + NWT + NW2; t += stride) {
        if (t < NB) {
            int jc = t >> 12, i = t & 4095;
            const int4* ap = (const int4*)(adj + (size_t)i * NN + jc * 32);
            uint32_t w = 0;
#pragma unroll
            for (int q = 0; q < 8; ++q) {
                int4 a = ap[q];
                w |= (a.x > 0 ? 1u : 0u) << (q * 4 + 0);
                w |= (a.y > 0 ? 1u : 0u) << (q * 4 + 1);
                w |= (a.z > 0 ? 1u : 0u) << (q * 4 + 2);
                w |= (a.w > 0 ? 1u : 0u) << (q * 4 + 3);
            }
            bitsT[t] = w;
        } else if (t < NB + NXT) {
            size_t d = (size_t)(t - NB) * 8;
            int kc = (int)(d >> 17);
            int rem = (int)(d & 131071);
            int i = rem >> 5, k0 = rem & 31;
            const float* sp = x + (size_t)i * 512 + kc * 32 + k0;
            f32x4 s0 = *(const f32x4*)sp;
            f32x4 s1 = *(const f32x4*)(sp + 4);
            bf16x8 o;
#pragma unroll
            for (int e = 0; e < 4; ++e) { o[e] = (bf16_t)s0[e]; o[4 + e] = (bf16_t)s1[e]; }
            *(bf16x8*)(xbt + d) = o;
        } else if (t < NB + NXT + NWT) {
            size_t d = (size_t)(t - NB - NXT) * 8;
            int kc = (int)(d >> 14);
            int rem = (int)(d & 16383);
            int col = rem >> 5, k0 = rem & 31;
            int h = col >> 6, dd = col & 63;
            bf16x8 o;
#pragma unroll
            for (int e = 0; e < 8; ++e)
                o[e] = (bf16_t)Wh[(size_t)(h << 15) + (size_t)(kc * 32 + k0 + e) * 64 + dd];
            *(bf16x8*)(WT1t + d) = o;
        } else {
            int u = t - NB - NXT - NWT;
            int o2 = u >> 9, cc = u & 511;
            WoutT[u] = (bf16_t)Wo[cc * 128 + o2];
        }
    }
}

// ---- bf16 MFMA GEMM, 4 waves/block, wave = 16*RT rows x 64 cols.
// TILED=1: A/B read K-tiled [kc][row|col][32]; TILED=0: row-major (gemm2).
// CS: epilogue writes VTt as F16 (j-tiled [i>>5][col][i&31]) + g/E2/F2.
// WC: writes fp32 partial C slice (split-K via blockIdx.z)
template<int CS, int WC, int TILED, int RT>
__global__ __launch_bounds__(256) void gemm_k(const bf16_t* __restrict__ A,
                                              const bf16_t* __restrict__ BT,
                                              half_t* __restrict__ VTt,
                                              float* __restrict__ Cp,
                                              const float* __restrict__ a1,
                                              const float* __restrict__ a2,
                                              float* __restrict__ g1,
                                              float* __restrict__ E2,
                                              float* __restrict__ F2,
                                              int K, int NC, int kslice, int NCOLS) {
    const int wave = threadIdx.x >> 6, lane = threadIdx.x & 63;
    const int lr = lane & 15, kg = lane >> 4;
    const int rowb = (blockIdx.x * 4 + wave) * (16 * RT), cb = blockIdx.y * 64, kz = blockIdx.z;
    f32x4 acc[RT][4];
#pragma unroll
    for (int rt = 0; rt < RT; ++rt)
#pragma unroll
        for (int dt = 0; dt < 4; ++dt) acc[rt][dt] = 0.0f;
    const int k0beg = kz * kslice, k0end = k0beg + kslice;
    for (int k0 = k0beg; k0 < k0end; k0 += 32) {
        bf16x8 af[RT];
#pragma unroll
        for (int rt = 0; rt < RT; ++rt) {
            if (TILED) {
                const int kc = k0 >> 5;
                af[rt] = *(const bf16x8*)(A + (size_t)kc * (NN * 32) +
                                          (size_t)(rowb + rt * 16 + lr) * 32 + kg * 8);
            } else {
                af[rt] = *(const bf16x8*)(A + (size_t)(rowb + rt * 16 + lr) * K + k0 + kg * 8);
            }
        }
#pragma unroll
        for (int dt = 0; dt < 4; ++dt) {
            bf16x8 bfr;
            if (TILED) {
                const int kc = k0 >> 5;
                bfr = *(const bf16x8*)(BT + (size_t)kc * (NC * 32) +
                                       (size_t)(cb + dt * 16 + lr) * 32 + kg * 8);
            } else {
                bfr = *(const bf16x8*)(BT + (size_t)(cb + dt * 16 + lr) * K + k0 + kg * 8);
            }
#pragma unroll
            for (int rt = 0; rt < RT; ++rt)
                acc[rt][dt] = __builtin_amdgcn_mfma_f32_16x16x32_bf16(af[rt], bfr, acc[rt][dt], 0, 0, 0);
        }
    }
    if (WC) {
#pragma unroll
        for (int rt = 0; rt < RT; ++rt)
#pragma unroll
            for (int dt = 0; dt < 4; ++dt)
#pragma unroll
                for (int r = 0; r < 4; ++r)
                    Cp[((size_t)kz * NN + rowb + rt * 16 + kg * 4 + r) * NC + cb + dt * 16 + lr] = acc[rt][dt][r];
    }
    if (CS) {
        float a1v[4], a2v[4];
#pragma unroll
        for (int dt = 0; dt < 4; ++dt) {
            a1v[dt] = a1[cb + dt * 16 + lr];
            a2v[dt] = a2[cb + dt * 16 + lr];
        }
#pragma unroll
        for (int rt = 0; rt < RT; ++rt) {
            const int i0 = rowb + rt * 16 + kg * 4;
            const size_t tbase = (size_t)(i0 >> 5) * NCOLS * 32 + (i0 & 31);
#pragma unroll
            for (int dt = 0; dt < 4; ++dt) {
                f16x4 v;
#pragma unroll
                for (int r = 0; r < 4; ++r) v[r] = (half_t)acc[rt][dt][r];
                *(f16x4*)(VTt + tbase + (size_t)(cb + dt * 16 + lr) * 32) = v;
            }
#pragma unroll
            for (int r = 0; r < 4; ++r) {
                float d1 = 0.f, d2 = 0.f;
#pragma unroll
                for (int dt = 0; dt < 4; ++dt) { d1 += acc[rt][dt][r] * a1v[dt]; d2 += acc[rt][dt][r] * a2v[dt]; }
#pragma unroll
                for (int o = 1; o < 16; o <<= 1) { d1 += __shfl_xor(d1, o); d2 += __shfl_xor(d2, o); }
                if (lr == 0) {
                    size_t row = (size_t)blockIdx.y * NN + rowb + rt * 16 + kg * 4 + r;
                    g1[row] = exp2f(-0.8f * LOG2E * d1);
                    E2[row] = exp2f(LOG2E * d2);
                    F2[row] = exp2f(0.2f * LOG2E * d2);
                }
            }
        }
    }
}

// ---- fused attention-aggregate (R14 inner loop, NW waves/block).
// grid = (CG*JZG, 64); x -> (c = x/JZG, jzg = x%JZG); y = rowtile.
// NW waves/block; wave w owns jz = jzg*NW + w; wave = 64 rows x 64 cols.
// p'_ij = adj ? max(E2_j, g_i*F2_j) : 0  (f32 math, cvt f16, cndmask mask).
// Z row-sums via extra f16 MFMA against a ones-column B-fragment.
template<int NW, int JZG>
__global__ __launch_bounds__(64 * NW) void gat_agg_k(const float* __restrict__ g1,
                                                     const float* __restrict__ E2,
                                                     const float* __restrict__ F2, int shead,
                                                     const uint32_t* __restrict__ bitsT,
                                                     const half_t* __restrict__ VTt,
                                                     bf16_t* __restrict__ Hpart,
                                                     float* __restrict__ zpart,
                                                     int CT, int JR, int ZC, int TS) {
    const int wave = threadIdx.x >> 6, lane = threadIdx.x & 63;
    const int lr = lane & 15, kg = lane >> 4;
    const int c = blockIdx.x / JZG, jzg = blockIdx.x % JZG;
    const int rowb = blockIdx.y * 64;
    const int jz = jzg * NW + wave;
    const int cb = c * 64;
    const float* gp  = g1 + (size_t)shead * c;
    const float* E2p = E2 + (size_t)shead * c;
    const float* F2p = F2 + (size_t)shead * c;
    const int steps = JR >> 5, jb0 = jz * JR;

    f32x4 acc[4][4], accz[4];
#pragma unroll
    for (int rt = 0; rt < 4; ++rt) {
        accz[rt] = 0.0f;
#pragma unroll
        for (int dt = 0; dt < 4; ++dt) acc[rt][dt] = 0.0f;
    }
    float gv[4];
#pragma unroll
    for (int rt = 0; rt < 4; ++rt) gv[rt] = gp[rowb + rt * 16 + lr];
    f16x8 ones;
#pragma unroll
    for (int e = 0; e < 8; ++e) ones[e] = (half_t)(lr == 0 ? 1.0f : 0.0f);

    auto LOAD = [&](int jb, f16x8* bfr, f32x4& e2a, f32x4& e2b, f32x4& f2a, f32x4& f2b,
                    uint32_t* bw) {
        const int jk = jb + kg * 8;
        const int jc = jb >> 5;
        e2a = *(const f32x4*)(E2p + jk);
        e2b = *(const f32x4*)(E2p + jk + 4);
        f2a = *(const f32x4*)(F2p + jk);
        f2b = *(const f32x4*)(F2p + jk + 4);
        const half_t* vb = VTt + (size_t)jc * TS + kg * 8;
#pragma unroll
        for (int dt = 0; dt < 4; ++dt)
            bfr[dt] = *(const f16x8*)(vb + (size_t)(cb + dt * 16 + lr) * 32);
        const uint32_t* bb = bitsT + (size_t)jc * NN + rowb;
#pragma unroll
        for (int rt = 0; rt < 4; ++rt)
            bw[rt] = bb[rt * 16 + lr];
    };
    auto COMP = [&](const f16x8* bfr, f32x4 e2a, f32x4 e2b, f32x4 f2a, f32x4 f2b,
                    const uint32_t* bw) {
#pragma unroll
        for (int rt = 0; rt < 4; ++rt) {
            uint32_t mb = (bw[rt] >> (kg * 8)) & 0xffu;
            f16x8 af;
#pragma unroll
            for (int e = 0; e < 8; ++e) {
                float e2 = (e < 4) ? e2a[e] : e2b[e - 4];
                float f2 = (e < 4) ? f2a[e] : f2b[e - 4];
                float p = fmaxf(e2, gv[rt] * f2);
                p = (mb & (1u << e)) ? p : 0.0f;
                af[e] = (half_t)p;
            }
#pragma unroll
            for (int dt = 0; dt < 4; ++dt)
                acc[rt][dt] = __builtin_amdgcn_mfma_f32_16x16x32_f16(af, bfr[dt], acc[rt][dt], 0, 0, 0);
            accz[rt] = __builtin_amdgcn_mfma_f32_16x16x32_f16(af, ones, accz[rt], 0, 0, 0);
        }
    };

    f16x8 bA[4], bB[4];
    f32x4 eaA, ebA, faA, fbA, eaB, ebB, faB, fbB;
    uint32_t wA[4], wB[4];
    LOAD(jb0, bA, eaA, ebA, faA, fbA, wA);
    for (int js = 0; js < steps - 2; js += 2) {
        LOAD(jb0 + (js + 1) * 32, bB, eaB, ebB, faB, fbB, wB);
        COMP(bA, eaA, ebA, faA, fbA, wA);
        LOAD(jb0 + (js + 2) * 32, bA, eaA, ebA, faA, fbA, wA);
        COMP(bB, eaB, ebB, faB, fbB, wB);
    }
    LOAD(jb0 + (steps - 1) * 32, bB, eaB, ebB, faB, fbB, wB);
    COMP(bA, eaA, ebA, faA, fbA, wA);
    COMP(bB, eaB, ebB, faB, fbB, wB);

    bf16_t* Hp = Hpart + (size_t)jz * NN * CT;
#pragma unroll
    for (int rt = 0; rt < 4; ++rt) {
#pragma unroll
        for (int dt = 0; dt < 4; ++dt)
#pragma unroll
            for (int r = 0; r < 4; ++r)
                Hp[(size_t)(rowb + rt * 16 + kg * 4 + r) * CT + cb + dt * 16 + lr] = (bf16_t)acc[rt][dt][r];
    }
    if (lr == 0 && (ZC > 1 || c == 0)) {
        int zi = jz * ZC + (ZC > 1 ? c : 0);
#pragma unroll
        for (int rt = 0; rt < 4; ++rt)
#pragma unroll
            for (int r = 0; r < 4; ++r)
                zpart[(size_t)zi * NN + rowb + rt * 16 + kg * 4 + r] = accz[rt][r];
    }
}

// ---- finalize layer 1: hcatb = bf16(ELU(sum H / sum Z)), 8 cols/thread
__global__ __launch_bounds__(256) void fin1_k(const bf16_t* __restrict__ Hpart,
                                              const float* __restrict__ zpart,
                                              bf16_t* __restrict__ hcatb) {
    int idx = blockIdx.x * 256 + threadIdx.x;   // < N*64
    int i = idx >> 6, col0 = (idx & 63) << 3, h = col0 >> 6;
    float Z = 0.f;
#pragma unroll
    for (int jz = 0; jz < 4; ++jz) Z += zpart[(size_t)(jz * 8 + h) * NN + i];
    float hs[8];
#pragma unroll
    for (int e = 0; e < 8; ++e) hs[e] = 0.f;
#pragma unroll
    for (int jz = 0; jz < 4; ++jz) {
        bf16x8 v = *(const bf16x8*)(Hpart + ((size_t)jz * NN + i) * 512 + col0);
#pragma unroll
        for (int e = 0; e < 8; ++e) hs[e] += (float)v[e];
    }
    float invZ = 1.0f / Z;
    bf16x8 o;
#pragma unroll
    for (int e = 0; e < 8; ++e) {
        float v = hs[e] * invZ;
        o[e] = (bf16_t)(v > 0.f ? v : expm1f(v));
    }
    *(bf16x8*)(hcatb + (size_t)i * 512 + col0) = o;
}

// ---- combine split-K gemm2 slices: VT2t (j-tiled f16) + g/E2/F2. 128thr=1 row.
__global__ __launch_bounds__(128) void comb2_k(const float* __restrict__ Cp,
                                               const float* __restrict__ a1o,
                                               const float* __restrict__ a2o,
                                               half_t* __restrict__ VT2t,
                                               float* __restrict__ g1o,
                                               float* __restrict__ E2o,
                                               float* __restrict__ F2o) {
    int r = blockIdx.x, t = threadIdx.x;
    float w = 0.f;
#pragma unroll
    for (int z = 0; z < 4; ++z) w += Cp[((size_t)z * NN + r) * 128 + t];
    VT2t[(size_t)(r >> 5) * (128 * 32) + t * 32 + (r & 31)] = (half_t)w;
    float d1 = w * a1o[t], d2 = w * a2o[t];
#pragma unroll
    for (int o = 1; o < 64; o <<= 1) { d1 += __shfl_xor(d1, o); d2 += __shfl_xor(d2, o); }
    __shared__ float red[4];
    if ((t & 63) == 0) { red[(t >> 6) * 2 + 0] = d1; red[(t >> 6) * 2 + 1] = d2; }
    __syncthreads();
    if (t == 0) {
        float s1 = red[0] + red[2], s2 = red[1] + red[3];
        g1o[r] = exp2f(-0.8f * LOG2E * s1);
        E2o[r] = exp2f(LOG2E * s2);
        F2o[r] = exp2f(0.2f * LOG2E * s2);
    }
}

// ---- finalize layer 2: out fp32 = sum H / sum Z, 8 cols/thread
__global__ __launch_bounds__(256) void fin2_k(const bf16_t* __restrict__ Hpart,
                                              const float* __restrict__ zpart,
                                              float* __restrict__ out) {
    int idx = blockIdx.x * 256 + threadIdx.x;   // < N*16
    int i = idx >> 4, col0 = (idx & 15) << 3;
    float Z = 0.f;
#pragma unroll
    for (int jz = 0; jz < 16; ++jz) Z += zpart[(size_t)jz * NN + i];
    float hs[8];
#pragma unroll
    for (int e = 0; e < 8; ++e) hs[e] = 0.f;
#pragma unroll
    for (int jz = 0; jz < 16; ++jz) {
        bf16x8 v = *(const bf16x8*)(Hpart + ((size_t)jz * NN + i) * 128 + col0);
#pragma unroll
        for (int e = 0; e < 8; ++e) hs[e] += (float)v[e];
    }
    float invZ = 1.0f / Z;
    f32x4 o0, o1;
#pragma unroll
    for (int e = 0; e < 4; ++e) { o0[e] = hs[e] * invZ; o1[e] = hs[e + 4] * invZ; }
    *(f32x4*)(out + (size_t)i * 128 + col0) = o0;
    *(f32x4*)(out + (size_t)i * 128 + col0 + 4) = o1;
}

extern "C" void kernel_launch(void* const* d_in, const int* in_sizes, int n_in,
                              void* d_out, int out_size, void* d_ws, size_t ws_size,
                              hipStream_t stream) {
    const int N = 4096;
    const float* x       = (const float*)d_in[0];
    const int*   adj     = (const int*)d_in[1];
    const float* W_heads = (const float*)d_in[2];
    const float* a1h     = (const float*)d_in[3];
    const float* a2h     = (const float*)d_in[4];
    const float* W_out   = (const float*)d_in[5];
    const float* a1o     = (const float*)d_in[6];
    const float* a2o     = (const float*)d_in[7];
    (void)in_sizes; (void)n_in; (void)out_size; (void)ws_size;

    size_t off = 0;
    auto alloc = [&](size_t bytes) { size_t o = off; off = (off + bytes + 255) & ~(size_t)255; return o; };
    char* ws = (char*)d_ws;
    uint32_t* bitsT = (uint32_t*)(ws + alloc((size_t)N * N / 8));        // 2 MB
    half_t* VT1t    = (half_t*)(ws + alloc((size_t)512 * N * 2));        // 4 MB (j-tiled f16)
    bf16_t* hcatb   = (bf16_t*)(ws + alloc((size_t)N * 512 * 2));        // 4 MB
    bf16_t* WoutT   = (bf16_t*)(ws + alloc((size_t)128 * 512 * 2));      // 128 KB
    float*  g1h     = (float*)(ws + alloc((size_t)8 * N * 4));
    float*  E2h     = (float*)(ws + alloc((size_t)8 * N * 4));
    float*  F2h     = (float*)(ws + alloc((size_t)8 * N * 4));
    float*  g1o     = (float*)(ws + alloc((size_t)N * 4));
    float*  E2o     = (float*)(ws + alloc((size_t)N * 4));
    float*  F2o     = (float*)(ws + alloc((size_t)N * 4));
    half_t* VT2t    = (half_t*)(ws + alloc((size_t)128 * N * 2));        // 1 MB (j-tiled f16)
    float*  zpart   = (float*)(ws + alloc((size_t)64 * N * 4));         // 1 MB
    bf16_t* Hpart   = (bf16_t*)(ws + alloc((size_t)32 * 1024 * 1024));   // 32 MB (16 used L1)
    // aliases into the Hpart region (temporally disjoint):
    bf16_t* xbt   = (bf16_t*)Hpart;                       // 4 MB, dead after gemm1
    bf16_t* WT1t  = (bf16_t*)((char*)Hpart + (9 << 20));  // 0.5 MB, dead after gemm1
    float*  Cpart = (float*)Hpart;                        // gemm2..comb2 only

    // 1. fused prep: bitsT + K-tiled bf16 xbt/WT1t + row-major WoutT
    hipLaunchKernelGGL(prep_k, dim3(2048), dim3(256), 0, stream,
                       adj, x, W_heads, W_out, bitsT, xbt, WT1t, WoutT);
    // 2. gemm1 (TILED inputs, RT=2): VT1t (f16) + g/E2/F2 per head
    hipLaunchKernelGGL((gemm_k<1, 0, 1, 2>), dim3(32, 8, 1), dim3(256), 0, stream,
                       xbt, WT1t, VT1t, (float*)nullptr, a1h, a2h, g1h, E2h, F2h, 512, 512, 512, 512);
    // 3. layer-1 aggregate: 4-wave blocks, grid x=head(8), y=rowtile(64); jz=wave 0..3, JR=1024
    hipLaunchKernelGGL((gat_agg_k<4, 1>), dim3(8, 64, 1), dim3(256), 0, stream,
                       g1h, E2h, F2h, N, bitsT, VT1t, Hpart, zpart, 512, 1024, 8, 512 * 32);
    // 4. finalize 1 -> hcatb
    hipLaunchKernelGGL(fin1_k, dim3(1024), dim3(256), 0, stream, Hpart, zpart, hcatb);
    // 5. gemm2 split-K=4 (row-major inputs, RT=1) -> Cpart
    hipLaunchKernelGGL((gemm_k<0, 1, 0, 1>), dim3(64, 2, 4), dim3(256), 0, stream,
                       hcatb, WoutT, (half_t*)nullptr, Cpart,
                       (const float*)nullptr, (const float*)nullptr,
                       (float*)nullptr, (float*)nullptr, (float*)nullptr, 512, 128, 128, 128);
    // 6. combine -> VT2t (f16), g1o/E2o/F2o
    hipLaunchKernelGGL(comb2_k, dim3(4096), dim3(128), 0, stream, Cpart, a1o, a2o, VT2t, g1o, E2o, F2o);
    // 7. layer-2 aggregate: 4-wave blocks, grid x=(c,jzgrp)=8, y=rowtile(64); JR=256
    hipLaunchKernelGGL((gat_agg_k<4, 4>), dim3(8, 64, 1), dim3(256), 0, stream,
                       g1o, E2o, F2o, 0, bitsT, VT2t, Hpart, zpart, 128, 256, 1, 128 * 32);
    // 8. finalize 2 -> out
    hipLaunchKernelGGL(fin2_k, dim3(256), dim3(256), 0, stream, Hpart, zpart, (float*)d_out);
}

// Round 20
// 118.668 us; speedup vs baseline: 1.1896x; 1.0258x over previous
//
#include <hip/hip_runtime.h>
#include <hip/hip_bf16.h>
#include <cstdint>

// ---------------------------------------------------------------------------
// GAT forward, N=4096, F=512, D=64, H=8, O=128, fp32 in/out.
// Identity: exp(lrelu(u)) = max(exp(u), exp(0.2u)); u = s1_i+s2_j rank-1;
// softmax row-scale invariance => p'_ij = max(E2_j, g_i*F2_j), g=exp(-0.8 s1).
// Round-20 = Round-19 (best: 121.7us) + gemm2 operand-path fix:
//   RT=2 (32 rows/wave) + K-tiled A (hcatt, written tiled by fin1) and
//   B (WoutTt, written tiled by prep) -> dense fragment loads (R9/R13 lever).
// Agg kernels byte-identical to R19 (47.2us plateau, issue-port ~76% busy).
// ---------------------------------------------------------------------------

using bf16_t = __bf16;
using half_t = _Float16;
using bf16x4 = __attribute__((ext_vector_type(4))) __bf16;
using bf16x8 = __attribute__((ext_vector_type(8))) __bf16;
using f16x4  = __attribute__((ext_vector_type(4))) _Float16;
using f16x8  = __attribute__((ext_vector_type(8))) _Float16;
using f32x4  = __attribute__((ext_vector_type(4))) float;

#define LOG2E 1.44269504f
constexpr int NN = 4096;

// ---- fused prep: adjacency -> transposed bitmask (1 word/thread),
//      x -> xbt (K-tiled bf16 [kc][4096][32]), W_heads -> WT1t ([kc][512][32]),
//      W_out -> WoutTt ([kc][128][32], K-tiled).
__global__ __launch_bounds__(256) void prep_k(const int* __restrict__ adj,
                                              const float* __restrict__ x,
                                              const float* __restrict__ Wh,
                                              const float* __restrict__ Wo,
                                              uint32_t* __restrict__ bitsT,
                                              bf16_t* __restrict__ xbt,
                                              bf16_t* __restrict__ WT1t,
                                              bf16_t* __restrict__ WoutTt) {
    const int NB  = NN * NN / 32;
    const int NXT = NN * 512 / 8;
    const int NWT = 512 * 512 / 8;
    const int NW2 = 128 * 512 / 8;
    int stride = gridDim.x * blockDim.x;
    for (int t = blockIdx.x * blockDim.x + threadIdx.x; t < NB + NXT + NWT + NW2; t += stride) {
        if (t < NB) {
            int jc = t >> 12, i = t & 4095;
            const int4* ap = (const int4*)(adj + (size_t)i * NN + jc * 32);
            uint32_t w = 0;
#pragma unroll
            for (int q = 0; q < 8; ++q) {
                int4 a = ap[q];
                w |= (a.x > 0 ? 1u : 0u) << (q * 4 + 0);
                w |= (a.y > 0 ? 1u : 0u) << (q * 4 + 1);
                w |= (a.z > 0 ? 1u : 0u) << (q * 4 + 2);
                w |= (a.w > 0 ? 1u : 0u) << (q * 4 + 3);
            }
            bitsT[t] = w;
        } else if (t < NB + NXT) {
            size_t d = (size_t)(t - NB) * 8;
            int kc = (int)(d >> 17);
            int rem = (int)(d & 131071);
            int i = rem >> 5, k0 = rem & 31;
            const float* sp = x + (size_t)i * 512 + kc * 32 + k0;
            f32x4 s0 = *(const f32x4*)sp;
            f32x4 s1 = *(const f32x4*)(sp + 4);
            bf16x8 o;
#pragma unroll
            for (int e = 0; e < 4; ++e) { o[e] = (bf16_t)s0[e]; o[4 + e] = (bf16_t)s1[e]; }
            *(bf16x8*)(xbt + d) = o;
        } else if (t < NB + NXT + NWT) {
            size_t d = (size_t)(t - NB - NXT) * 8;
            int kc = (int)(d >> 14);
            int rem = (int)(d & 16383);
            int col = rem >> 5, k0 = rem & 31;
            int h = col >> 6, dd = col & 63;
            bf16x8 o;
#pragma unroll
            for (int e = 0; e < 8; ++e)
                o[e] = (bf16_t)Wh[(size_t)(h << 15) + (size_t)(kc * 32 + k0 + e) * 64 + dd];
            *(bf16x8*)(WT1t + d) = o;
        } else {
            size_t d = (size_t)(t - NB - NXT - NWT) * 8;
            int kc = (int)(d >> 12);             // / (128*32)
            int rem = (int)(d & 4095);
            int o2 = rem >> 5, k0 = rem & 31;
            bf16x8 o;
#pragma unroll
            for (int e = 0; e < 8; ++e)
                o[e] = (bf16_t)Wo[(size_t)(kc * 32 + k0 + e) * 128 + o2];
            *(bf16x8*)(WoutTt + d) = o;
        }
    }
}

// ---- bf16 MFMA GEMM, 4 waves/block, wave = 16*RT rows x 64 cols.
// TILED=1: A/B read K-tiled [kc][row|col][32]; TILED=0: row-major.
// CS: epilogue writes VTt as F16 (j-tiled [i>>5][col][i&31]) + g/E2/F2.
// WC: writes fp32 partial C slice (split-K via blockIdx.z)
template<int CS, int WC, int TILED, int RT>
__global__ __launch_bounds__(256) void gemm_k(const bf16_t* __restrict__ A,
                                              const bf16_t* __restrict__ BT,
                                              half_t* __restrict__ VTt,
                                              float* __restrict__ Cp,
                                              const float* __restrict__ a1,
                                              const float* __restrict__ a2,
                                              float* __restrict__ g1,
                                              float* __restrict__ E2,
                                              float* __restrict__ F2,
                                              int K, int NC, int kslice, int NCOLS) {
    const int wave = threadIdx.x >> 6, lane = threadIdx.x & 63;
    const int lr = lane & 15, kg = lane >> 4;
    const int rowb = (blockIdx.x * 4 + wave) * (16 * RT), cb = blockIdx.y * 64, kz = blockIdx.z;
    f32x4 acc[RT][4];
#pragma unroll
    for (int rt = 0; rt < RT; ++rt)
#pragma unroll
        for (int dt = 0; dt < 4; ++dt) acc[rt][dt] = 0.0f;
    const int k0beg = kz * kslice, k0end = k0beg + kslice;
    for (int k0 = k0beg; k0 < k0end; k0 += 32) {
        bf16x8 af[RT];
#pragma unroll
        for (int rt = 0; rt < RT; ++rt) {
            if (TILED) {
                const int kc = k0 >> 5;
                af[rt] = *(const bf16x8*)(A + (size_t)kc * (NN * 32) +
                                          (size_t)(rowb + rt * 16 + lr) * 32 + kg * 8);
            } else {
                af[rt] = *(const bf16x8*)(A + (size_t)(rowb + rt * 16 + lr) * K + k0 + kg * 8);
            }
        }
#pragma unroll
        for (int dt = 0; dt < 4; ++dt) {
            bf16x8 bfr;
            if (TILED) {
                const int kc = k0 >> 5;
                bfr = *(const bf16x8*)(BT + (size_t)kc * (NC * 32) +
                                       (size_t)(cb + dt * 16 + lr) * 32 + kg * 8);
            } else {
                bfr = *(const bf16x8*)(BT + (size_t)(cb + dt * 16 + lr) * K + k0 + kg * 8);
            }
#pragma unroll
            for (int rt = 0; rt < RT; ++rt)
                acc[rt][dt] = __builtin_amdgcn_mfma_f32_16x16x32_bf16(af[rt], bfr, acc[rt][dt], 0, 0, 0);
        }
    }
    if (WC) {
#pragma unroll
        for (int rt = 0; rt < RT; ++rt)
#pragma unroll
            for (int dt = 0; dt < 4; ++dt)
#pragma unroll
                for (int r = 0; r < 4; ++r)
                    Cp[((size_t)kz * NN + rowb + rt * 16 + kg * 4 + r) * NC + cb + dt * 16 + lr] = acc[rt][dt][r];
    }
    if (CS) {
        float a1v[4], a2v[4];
#pragma unroll
        for (int dt = 0; dt < 4; ++dt) {
            a1v[dt] = a1[cb + dt * 16 + lr];
            a2v[dt] = a2[cb + dt * 16 + lr];
        }
#pragma unroll
        for (int rt = 0; rt < RT; ++rt) {
            const int i0 = rowb + rt * 16 + kg * 4;
            const size_t tbase = (size_t)(i0 >> 5) * NCOLS * 32 + (i0 & 31);
#pragma unroll
            for (int dt = 0; dt < 4; ++dt) {
                f16x4 v;
#pragma unroll
                for (int r = 0; r < 4; ++r) v[r] = (half_t)acc[rt][dt][r];
                *(f16x4*)(VTt + tbase + (size_t)(cb + dt * 16 + lr) * 32) = v;
            }
#pragma unroll
            for (int r = 0; r < 4; ++r) {
                float d1 = 0.f, d2 = 0.f;
#pragma unroll
                for (int dt = 0; dt < 4; ++dt) { d1 += acc[rt][dt][r] * a1v[dt]; d2 += acc[rt][dt][r] * a2v[dt]; }
#pragma unroll
                for (int o = 1; o < 16; o <<= 1) { d1 += __shfl_xor(d1, o); d2 += __shfl_xor(d2, o); }
                if (lr == 0) {
                    size_t row = (size_t)blockIdx.y * NN + rowb + rt * 16 + kg * 4 + r;
                    g1[row] = exp2f(-0.8f * LOG2E * d1);
                    E2[row] = exp2f(LOG2E * d2);
                    F2[row] = exp2f(0.2f * LOG2E * d2);
                }
            }
        }
    }
}

// ---- fused attention-aggregate (R14 inner loop, NW waves/block).
// grid = (CG*JZG, 64); x -> (c = x/JZG, jzg = x%JZG); y = rowtile.
// NW waves/block; wave w owns jz = jzg*NW + w; wave = 64 rows x 64 cols.
// p'_ij = adj ? max(E2_j, g_i*F2_j) : 0  (f32 math, cvt f16, cndmask mask).
// Z row-sums via extra f16 MFMA against a ones-column B-fragment.
template<int NW, int JZG>
__global__ __launch_bounds__(64 * NW) void gat_agg_k(const float* __restrict__ g1,
                                                     const float* __restrict__ E2,
                                                     const float* __restrict__ F2, int shead,
                                                     const uint32_t* __restrict__ bitsT,
                                                     const half_t* __restrict__ VTt,
                                                     bf16_t* __restrict__ Hpart,
                                                     float* __restrict__ zpart,
                                                     int CT, int JR, int ZC, int TS) {
    const int wave = threadIdx.x >> 6, lane = threadIdx.x & 63;
    const int lr = lane & 15, kg = lane >> 4;
    const int c = blockIdx.x / JZG, jzg = blockIdx.x % JZG;
    const int rowb = blockIdx.y * 64;
    const int jz = jzg * NW + wave;
    const int cb = c * 64;
    const float* gp  = g1 + (size_t)shead * c;
    const float* E2p = E2 + (size_t)shead * c;
    const float* F2p = F2 + (size_t)shead * c;
    const int steps = JR >> 5, jb0 = jz * JR;

    f32x4 acc[4][4], accz[4];
#pragma unroll
    for (int rt = 0; rt < 4; ++rt) {
        accz[rt] = 0.0f;
#pragma unroll
        for (int dt = 0; dt < 4; ++dt) acc[rt][dt] = 0.0f;
    }
    float gv[4];
#pragma unroll
    for (int rt = 0; rt < 4; ++rt) gv[rt] = gp[rowb + rt * 16 + lr];
    f16x8 ones;
#pragma unroll
    for (int e = 0; e < 8; ++e) ones[e] = (half_t)(lr == 0 ? 1.0f : 0.0f);

    auto LOAD = [&](int jb, f16x8* bfr, f32x4& e2a, f32x4& e2b, f32x4& f2a, f32x4& f2b,
                    uint32_t* bw) {
        const int jk = jb + kg * 8;
        const int jc = jb >> 5;
        e2a = *(const f32x4*)(E2p + jk);
        e2b = *(const f32x4*)(E2p + jk + 4);
        f2a = *(const f32x4*)(F2p + jk);
        f2b = *(const f32x4*)(F2p + jk + 4);
        const half_t* vb = VTt + (size_t)jc * TS + kg * 8;
#pragma unroll
        for (int dt = 0; dt < 4; ++dt)
            bfr[dt] = *(const f16x8*)(vb + (size_t)(cb + dt * 16 + lr) * 32);
        const uint32_t* bb = bitsT + (size_t)jc * NN + rowb;
#pragma unroll
        for (int rt = 0; rt < 4; ++rt)
            bw[rt] = bb[rt * 16 + lr];
    };
    auto COMP = [&](const f16x8* bfr, f32x4 e2a, f32x4 e2b, f32x4 f2a, f32x4 f2b,
                    const uint32_t* bw) {
#pragma unroll
        for (int rt = 0; rt < 4; ++rt) {
            uint32_t mb = (bw[rt] >> (kg * 8)) & 0xffu;
            f16x8 af;
#pragma unroll
            for (int e = 0; e < 8; ++e) {
                float e2 = (e < 4) ? e2a[e] : e2b[e - 4];
                float f2 = (e < 4) ? f2a[e] : f2b[e - 4];
                float p = fmaxf(e2, gv[rt] * f2);
                p = (mb & (1u << e)) ? p : 0.0f;
                af[e] = (half_t)p;
            }
#pragma unroll
            for (int dt = 0; dt < 4; ++dt)
                acc[rt][dt] = __builtin_amdgcn_mfma_f32_16x16x32_f16(af, bfr[dt], acc[rt][dt], 0, 0, 0);
            accz[rt] = __builtin_amdgcn_mfma_f32_16x16x32_f16(af, ones, accz[rt], 0, 0, 0);
        }
    };

    f16x8 bA[4], bB[4];
    f32x4 eaA, ebA, faA, fbA, eaB, ebB, faB, fbB;
    uint32_t wA[4], wB[4];
    LOAD(jb0, bA, eaA, ebA, faA, fbA, wA);
    for (int js = 0; js < steps - 2; js += 2) {
        LOAD(jb0 + (js + 1) * 32, bB, eaB, ebB, faB, fbB, wB);
        COMP(bA, eaA, ebA, faA, fbA, wA);
        LOAD(jb0 + (js + 2) * 32, bA, eaA, ebA, faA, fbA, wA);
        COMP(bB, eaB, ebB, faB, fbB, wB);
    }
    LOAD(jb0 + (steps - 1) * 32, bB, eaB, ebB, faB, fbB, wB);
    COMP(bA, eaA, ebA, faA, fbA, wA);
    COMP(bB, eaB, ebB, faB, fbB, wB);

    bf16_t* Hp = Hpart + (size_t)jz * NN * CT;
#pragma unroll
    for (int rt = 0; rt < 4; ++rt) {
#pragma unroll
        for (int dt = 0; dt < 4; ++dt)
#pragma unroll
            for (int r = 0; r < 4; ++r)
                Hp[(size_t)(rowb + rt * 16 + kg * 4 + r) * CT + cb + dt * 16 + lr] = (bf16_t)acc[rt][dt][r];
    }
    if (lr == 0 && (ZC > 1 || c == 0)) {
        int zi = jz * ZC + (ZC > 1 ? c : 0);
#pragma unroll
        for (int rt = 0; rt < 4; ++rt)
#pragma unroll
            for (int r = 0; r < 4; ++r)
                zpart[(size_t)zi * NN + rowb + rt * 16 + kg * 4 + r] = accz[rt][r];
    }
}

// ---- finalize layer 1: hcatt (K-tiled bf16) = ELU(sum H / sum Z), 8 cols/thread
__global__ __launch_bounds__(256) void fin1_k(const bf16_t* __restrict__ Hpart,
                                              const float* __restrict__ zpart,
                                              bf16_t* __restrict__ hcatt) {
    int idx = blockIdx.x * 256 + threadIdx.x;   // < N*64
    int i = idx >> 6, col0 = (idx & 63) << 3, h = col0 >> 6;
    float Z = 0.f;
#pragma unroll
    for (int jz = 0; jz < 4; ++jz) Z += zpart[(size_t)(jz * 8 + h) * NN + i];
    float hs[8];
#pragma unroll
    for (int e = 0; e < 8; ++e) hs[e] = 0.f;
#pragma unroll
    for (int jz = 0; jz < 4; ++jz) {
        bf16x8 v = *(const bf16x8*)(Hpart + ((size_t)jz * NN + i) * 512 + col0);
#pragma unroll
        for (int e = 0; e < 8; ++e) hs[e] += (float)v[e];
    }
    float invZ = 1.0f / Z;
    bf16x8 o;
#pragma unroll
    for (int e = 0; e < 8; ++e) {
        float v = hs[e] * invZ;
        o[e] = (bf16_t)(v > 0.f ? v : expm1f(v));
    }
    // K-tiled write: [col0>>5][i][col0&31], 8 contiguous along k
    *(bf16x8*)(hcatt + (size_t)(col0 >> 5) * (NN * 32) + (size_t)i * 32 + (col0 & 31)) = o;
}

// ---- combine split-K gemm2 slices: VT2t (j-tiled f16) + g/E2/F2. 128thr=1 row.
__global__ __launch_bounds__(128) void comb2_k(const float* __restrict__ Cp,
                                               const float* __restrict__ a1o,
                                               const float* __restrict__ a2o,
                                               half_t* __restrict__ VT2t,
                                               float* __restrict__ g1o,
                                               float* __restrict__ E2o,
                                               float* __restrict__ F2o) {
    int r = blockIdx.x, t = threadIdx.x;
    float w = 0.f;
#pragma unroll
    for (int z = 0; z < 4; ++z) w += Cp[((size_t)z * NN + r) * 128 + t];
    VT2t[(size_t)(r >> 5) * (128 * 32) + t * 32 + (r & 31)] = (half_t)w;
    float d1 = w * a1o[t], d2 = w * a2o[t];
#pragma unroll
    for (int o = 1; o < 64; o <<= 1) { d1 += __shfl_xor(d1, o); d2 += __shfl_xor(d2, o); }
    __shared__ float red[4];
    if ((t & 63) == 0) { red[(t >> 6) * 2 + 0] = d1; red[(t >> 6) * 2 + 1] = d2; }
    __syncthreads();
    if (t == 0) {
        float s1 = red[0] + red[2], s2 = red[1] + red[3];
        g1o[r] = exp2f(-0.8f * LOG2E * s1);
        E2o[r] = exp2f(LOG2E * s2);
        F2o[r] = exp2f(0.2f * LOG2E * s2);
    }
}

// ---- finalize layer 2: out fp32 = sum H / sum Z, 8 cols/thread
__global__ __launch_bounds__(256) void fin2_k(const bf16_t* __restrict__ Hpart,
                                              const float* __restrict__ zpart,
                                              float* __restrict__ out) {
    int idx = blockIdx.x * 256 + threadIdx.x;   // < N*16
    int i = idx >> 4, col0 = (idx & 15) << 3;
    float Z = 0.f;
#pragma unroll
    for (int jz = 0; jz < 16; ++jz) Z += zpart[(size_t)jz * NN + i];
    float hs[8];
#pragma unroll
    for (int e = 0; e < 8; ++e) hs[e] = 0.f;
#pragma unroll
    for (int jz = 0; jz < 16; ++jz) {
        bf16x8 v = *(const bf16x8*)(Hpart + ((size_t)jz * NN + i) * 128 + col0);
#pragma unroll
        for (int e = 0; e < 8; ++e) hs[e] += (float)v[e];
    }
    float invZ = 1.0f / Z;
    f32x4 o0, o1;
#pragma unroll
    for (int e = 0; e < 4; ++e) { o0[e] = hs[e] * invZ; o1[e] = hs[e + 4] * invZ; }
    *(f32x4*)(out + (size_t)i * 128 + col0) = o0;
    *(f32x4*)(out + (size_t)i * 128 + col0 + 4) = o1;
}

extern "C" void kernel_launch(void* const* d_in, const int* in_sizes, int n_in,
                              void* d_out, int out_size, void* d_ws, size_t ws_size,
                              hipStream_t stream) {
    const int N = 4096;
    const float* x       = (const float*)d_in[0];
    const int*   adj     = (const int*)d_in[1];
    const float* W_heads = (const float*)d_in[2];
    const float* a1h     = (const float*)d_in[3];
    const float* a2h     = (const float*)d_in[4];
    const float* W_out   = (const float*)d_in[5];
    const float* a1o     = (const float*)d_in[6];
    const float* a2o     = (const float*)d_in[7];
    (void)in_sizes; (void)n_in; (void)out_size; (void)ws_size;

    size_t off = 0;
    auto alloc = [&](size_t bytes) { size_t o = off; off = (off + bytes + 255) & ~(size_t)255; return o; };
    char* ws = (char*)d_ws;
    uint32_t* bitsT = (uint32_t*)(ws + alloc((size_t)N * N / 8));        // 2 MB
    half_t* VT1t    = (half_t*)(ws + alloc((size_t)512 * N * 2));        // 4 MB (j-tiled f16)
    bf16_t* hcatt   = (bf16_t*)(ws + alloc((size_t)N * 512 * 2));        // 4 MB (K-tiled)
    bf16_t* WoutTt  = (bf16_t*)(ws + alloc((size_t)128 * 512 * 2));      // 128 KB (K-tiled)
    float*  g1h     = (float*)(ws + alloc((size_t)8 * N * 4));
    float*  E2h     = (float*)(ws + alloc((size_t)8 * N * 4));
    float*  F2h     = (float*)(ws + alloc((size_t)8 * N * 4));
    float*  g1o     = (float*)(ws + alloc((size_t)N * 4));
    float*  E2o     = (float*)(ws + alloc((size_t)N * 4));
    float*  F2o     = (float*)(ws + alloc((size_t)N * 4));
    half_t* VT2t    = (half_t*)(ws + alloc((size_t)128 * N * 2));        // 1 MB (j-tiled f16)
    float*  zpart   = (float*)(ws + alloc((size_t)64 * N * 4));          // 1 MB
    bf16_t* Hpart   = (bf16_t*)(ws + alloc((size_t)32 * 1024 * 1024));   // 32 MB (16 used L1)
    // aliases into the Hpart region (temporally disjoint):
    bf16_t* xbt   = (bf16_t*)Hpart;                       // 4 MB, dead after gemm1
    bf16_t* WT1t  = (bf16_t*)((char*)Hpart + (9 << 20));  // 0.5 MB, dead after gemm1
    float*  Cpart = (float*)Hpart;                        // gemm2..comb2 only

    // 1. fused prep: bitsT + K-tiled bf16 xbt/WT1t/WoutTt
    hipLaunchKernelGGL(prep_k, dim3(2048), dim3(256), 0, stream,
                       adj, x, W_heads, W_out, bitsT, xbt, WT1t, WoutTt);
    // 2. gemm1 (TILED, RT=2): VT1t (f16) + g/E2/F2 per head
    hipLaunchKernelGGL((gemm_k<1, 0, 1, 2>), dim3(32, 8, 1), dim3(256), 0, stream,
                       xbt, WT1t, VT1t, (float*)nullptr, a1h, a2h, g1h, E2h, F2h, 512, 512, 512, 512);
    // 3. layer-1 aggregate: 4-wave blocks, grid x=head(8), y=rowtile(64); jz=wave 0..3, JR=1024
    hipLaunchKernelGGL((gat_agg_k<4, 1>), dim3(8, 64, 1), dim3(256), 0, stream,
                       g1h, E2h, F2h, N, bitsT, VT1t, Hpart, zpart, 512, 1024, 8, 512 * 32);
    // 4. finalize 1 -> hcatt (K-tiled)
    hipLaunchKernelGGL(fin1_k, dim3(1024), dim3(256), 0, stream, Hpart, zpart, hcatt);
    // 5. gemm2 split-K=4 (TILED, RT=2) -> Cpart
    hipLaunchKernelGGL((gemm_k<0, 1, 1, 2>), dim3(32, 2, 4), dim3(256), 0, stream,
                       hcatt, WoutTt, (half_t*)nullptr, Cpart,
                       (const float*)nullptr, (const float*)nullptr,
                       (float*)nullptr, (float*)nullptr, (float*)nullptr, 512, 128, 128, 128);
    // 6. combine -> VT2t (f16), g1o/E2o/F2o
    hipLaunchKernelGGL(comb2_k, dim3(4096), dim3(128), 0, stream, Cpart, a1o, a2o, VT2t, g1o, E2o, F2o);
    // 7. layer-2 aggregate: 4-wave blocks, grid x=(c,jzgrp)=8, y=rowtile(64); JR=256
    hipLaunchKernelGGL((gat_agg_k<4, 4>), dim3(8, 64, 1), dim3(256), 0, stream,
                       g1o, E2o, F2o, 0, bitsT, VT2t, Hpart, zpart, 128, 256, 1, 128 * 32);
    // 8. finalize 2 -> out
    hipLaunchKernelGGL(fin2_k, dim3(256), dim3(256), 0, stream, Hpart, zpart, (float*)d_out);
}